// Round 3
// baseline (574.708 us; speedup 1.0000x reference)
//
#include <hip/hip_runtime.h>
#include <cstdint>
#include <cstddef>

typedef float f32x4 __attribute__((ext_vector_type(4)));
typedef short s16x8 __attribute__((ext_vector_type(8)));
typedef short s16x4 __attribute__((ext_vector_type(4)));

#define DEV static __device__ __forceinline__

DEV float bf2f(short s) {
  union { unsigned u; float f; } c;
  c.u = ((unsigned)(unsigned short)s) << 16;
  return c.f;
}
DEV short f2bf(float f) {
  union { float f; unsigned u; } c;
  c.f = f;
  unsigned r = c.u + 0x7fffu + ((c.u >> 16) & 1u);
  return (short)(r >> 16);
}
DEV float wave_allsum(float v) {
#pragma unroll
  for (int off = 32; off > 0; off >>= 1) v += __shfl_xor(v, off, 64);
  return v;
}
DEV void gload_lds16(const void* g, void* l) {
  __builtin_amdgcn_global_load_lds(
      (const __attribute__((address_space(1))) void*)g,
      (__attribute__((address_space(3))) void*)l, 16, 0, 0);
}
DEV float silu_f(float g) { return g / (1.f + __expf(-g)); }

// bijective XCD-chunk swizzle (m204)
DEV int xcd_swizzle(int orig, int nwg) {
  int q = nwg >> 3, r = nwg & 7;
  int xcd = orig & 7, pos = orig >> 3;
  return (xcd < r ? xcd * (q + 1) : r * (q + 1) + (xcd - r) * q) + pos;
}

// ---------------- bf16 GEMM: C = A(MxK) @ W(NxK)^T, fused epilogues ---------
// 128x128 tile, BK=64, 4 waves, global_load_lds(16B) staging, XOR k-group
// swizzle (linear LDS dest + inverse-swizzled global src + swizzled ds_read).
enum { EPI_BF16 = 0, EPI_BIAS_BF16 = 1, EPI_SCATTER = 4, EPI_ADDOUT = 5 };

template <int EPI>
__global__ __launch_bounds__(256) void gemm_bt(
    const short* __restrict__ A, const short* __restrict__ W,
    const float* __restrict__ bias, void* __restrict__ outp,
    int M, int N, int K)
{
  __shared__ short As[128 * 64];
  __shared__ short Bs[128 * 64];
  const int tid = threadIdx.x;
  const int wave = tid >> 6, lane = tid & 63;
  const int nwg = gridDim.x * gridDim.y;
  const int orig = blockIdx.y * gridDim.x + blockIdx.x;
  const int wg = xcd_swizzle(orig, nwg);
  const int row0 = (wg / gridDim.x) * 128, col0 = (wg % gridDim.x) * 128;
  const int wr = wave >> 1, wc = wave & 1;

  f32x4 acc[4][4];
#pragma unroll
  for (int m = 0; m < 4; ++m)
#pragma unroll
    for (int n = 0; n < 4; ++n) acc[m][n] = f32x4{0.f, 0.f, 0.f, 0.f};

  int srow[4], skg[4];
#pragma unroll
  for (int i = 0; i < 4; ++i) {
    int e = i * 2048 + tid * 8;
    srow[i] = e >> 6;
    skg[i] = ((e >> 3) & 7) ^ (srow[i] & 7);
  }

  for (int kt = 0; kt < K; kt += 64) {
#pragma unroll
    for (int i = 0; i < 4; ++i)
      gload_lds16(A + (size_t)(row0 + srow[i]) * K + kt + skg[i] * 8,
                  &As[i * 2048 + wave * 512]);
#pragma unroll
    for (int i = 0; i < 4; ++i)
      gload_lds16(W + (size_t)(col0 + srow[i]) * K + kt + skg[i] * 8,
                  &Bs[i * 2048 + wave * 512]);
    __syncthreads();
#pragma unroll
    for (int ks = 0; ks < 2; ++ks) {
      s16x8 af[4], bfr[4];
#pragma unroll
      for (int m = 0; m < 4; ++m) {
        int row = wr * 64 + m * 16 + (lane & 15);
        int kg = (ks * 4 + (lane >> 4)) ^ (row & 7);
        af[m] = *(const s16x8*)&As[row * 64 + kg * 8];
      }
#pragma unroll
      for (int n = 0; n < 4; ++n) {
        int col = wc * 64 + n * 16 + (lane & 15);
        int kg = (ks * 4 + (lane >> 4)) ^ (col & 7);
        bfr[n] = *(const s16x8*)&Bs[col * 64 + kg * 8];
      }
#pragma unroll
      for (int m = 0; m < 4; ++m)
#pragma unroll
        for (int n = 0; n < 4; ++n)
          acc[m][n] = __builtin_amdgcn_mfma_f32_16x16x32_bf16(af[m], bfr[n], acc[m][n], 0, 0, 0);
    }
    __syncthreads();
  }

  const int lr = (lane >> 4) * 4, lc = lane & 15;
#pragma unroll
  for (int m = 0; m < 4; ++m) {
#pragma unroll
    for (int i = 0; i < 4; ++i) {
      int gr = row0 + wr * 64 + m * 16 + lr + i;
      size_t orow;
      if (EPI == EPI_SCATTER) {
        int b = gr / 900, rem = gr % 900;
        int w = rem / 9, n_ = rem % 9;
        int wi = w / 10, wj = w % 10;
        int ii = n_ / 3, jj = n_ % 3;
        int gy = wi * 3 + ii + 1; if (gy >= 30) gy -= 30;
        int gx = wj * 3 + jj + 1; if (gx >= 30) gx -= 30;
        orow = (size_t)b * 900 + gy * 30 + gx;
      } else {
        orow = (size_t)gr;
      }
#pragma unroll
      for (int n = 0; n < 4; ++n) {
        int gc = col0 + wc * 64 + n * 16 + lc;
        float v = acc[m][n][i];
        if (EPI == EPI_BIAS_BF16 || EPI == EPI_SCATTER) v += bias[gc];
        if (EPI == EPI_ADDOUT) {
          float* po = (float*)outp;
          size_t oi = orow * (size_t)N + gc;
          po[oi] = po[oi] + v;   // each output element owned by exactly one block
        } else {
          ((short*)outp)[orow * (size_t)N + gc] = f2bf(v);
        }
      }
    }
  }
}

// ---------------- fused gate/up SwiGLU GEMM: out = silu(A@Wg^T) * (A@Wu^T) --
__global__ __launch_bounds__(256) void gemm_gu(
    const short* __restrict__ A, const short* __restrict__ Wg,
    const short* __restrict__ Wu, short* __restrict__ outp, int M, int K)
{
  __shared__ short As[128 * 64];
  __shared__ short Bg[128 * 64];
  __shared__ short Bu[128 * 64];
  const int tid = threadIdx.x;
  const int wave = tid >> 6, lane = tid & 63;
  const int nwg = gridDim.x * gridDim.y;
  const int orig = blockIdx.y * gridDim.x + blockIdx.x;
  const int wg = xcd_swizzle(orig, nwg);
  const int row0 = (wg / gridDim.x) * 128, col0 = (wg % gridDim.x) * 128;
  const int wr = wave >> 1, wc = wave & 1;

  f32x4 accg[4][4], accu[4][4];
#pragma unroll
  for (int m = 0; m < 4; ++m)
#pragma unroll
    for (int n = 0; n < 4; ++n) {
      accg[m][n] = f32x4{0.f, 0.f, 0.f, 0.f};
      accu[m][n] = f32x4{0.f, 0.f, 0.f, 0.f};
    }

  int srow[4], skg[4];
#pragma unroll
  for (int i = 0; i < 4; ++i) {
    int e = i * 2048 + tid * 8;
    srow[i] = e >> 6;
    skg[i] = ((e >> 3) & 7) ^ (srow[i] & 7);
  }

  for (int kt = 0; kt < K; kt += 64) {
#pragma unroll
    for (int i = 0; i < 4; ++i)
      gload_lds16(A + (size_t)(row0 + srow[i]) * K + kt + skg[i] * 8,
                  &As[i * 2048 + wave * 512]);
#pragma unroll
    for (int i = 0; i < 4; ++i)
      gload_lds16(Wg + (size_t)(col0 + srow[i]) * K + kt + skg[i] * 8,
                  &Bg[i * 2048 + wave * 512]);
#pragma unroll
    for (int i = 0; i < 4; ++i)
      gload_lds16(Wu + (size_t)(col0 + srow[i]) * K + kt + skg[i] * 8,
                  &Bu[i * 2048 + wave * 512]);
    __syncthreads();
#pragma unroll
    for (int ks = 0; ks < 2; ++ks) {
      s16x8 af[4], bg[4], bu[4];
#pragma unroll
      for (int m = 0; m < 4; ++m) {
        int row = wr * 64 + m * 16 + (lane & 15);
        int kg = (ks * 4 + (lane >> 4)) ^ (row & 7);
        af[m] = *(const s16x8*)&As[row * 64 + kg * 8];
      }
#pragma unroll
      for (int n = 0; n < 4; ++n) {
        int col = wc * 64 + n * 16 + (lane & 15);
        int kg = (ks * 4 + (lane >> 4)) ^ (col & 7);
        bg[n] = *(const s16x8*)&Bg[col * 64 + kg * 8];
        bu[n] = *(const s16x8*)&Bu[col * 64 + kg * 8];
      }
#pragma unroll
      for (int m = 0; m < 4; ++m)
#pragma unroll
        for (int n = 0; n < 4; ++n) {
          accg[m][n] = __builtin_amdgcn_mfma_f32_16x16x32_bf16(af[m], bg[n], accg[m][n], 0, 0, 0);
          accu[m][n] = __builtin_amdgcn_mfma_f32_16x16x32_bf16(af[m], bu[n], accu[m][n], 0, 0, 0);
        }
    }
    __syncthreads();
  }

  const int lr = (lane >> 4) * 4, lc = lane & 15;
#pragma unroll
  for (int m = 0; m < 4; ++m) {
#pragma unroll
    for (int i = 0; i < 4; ++i) {
      int gr = row0 + wr * 64 + m * 16 + lr + i;
#pragma unroll
      for (int n = 0; n < 4; ++n) {
        int gc = col0 + wc * 64 + n * 16 + lc;
        float g = accg[m][n][i], u = accu[m][n][i];
        ((short*)outp)[(size_t)gr * 1536 + gc] = f2bf(silu_f(g) * u);
      }
    }
  }
}

// ---------------- weight / activation conversion ----------------
__global__ __launch_bounds__(256) void cvt4_kernel(const float* __restrict__ src,
                                                   short* __restrict__ dst, int n4) {
  int i = blockIdx.x * 256 + threadIdx.x;
  if (i >= n4) return;
  f32x4 v = *(const f32x4*)(src + (size_t)i * 4);
  s16x4 o;
#pragma unroll
  for (int e = 0; e < 4; ++e) o[e] = f2bf(v[e]);
  *(s16x4*)(dst + (size_t)i * 4) = o;
}

__global__ __launch_bounds__(256) void prefix_cvt_kernel(const float* __restrict__ hs,
                                                         short* __restrict__ dst) {
  int i = blockIdx.x * 256 + threadIdx.x;
  if (i >= 512 * 128) return;
  int r = i >> 7, c4 = i & 127;
  int b = r >> 4, t = r & 15;
  f32x4 v = *(const f32x4*)(hs + ((size_t)b * 916 + t) * 512 + c4 * 4);
  s16x4 o;
#pragma unroll
  for (int e = 0; e < 4; ++e) o[e] = f2bf(v[e]);
  *(s16x4*)(dst + (size_t)r * 512 + c4 * 4) = o;
}

__global__ __launch_bounds__(512) void mean_kernel(const float* __restrict__ hs,
                                                   float* __restrict__ m) {
  int b = blockIdx.x, d = threadIdx.x;
  float s = 0.f;
#pragma unroll
  for (int t = 0; t < 16; ++t) s += hs[((size_t)b * 916 + t) * 512 + d];
  m[b * 512 + d] = s * (1.f / 16.f);
}

__global__ __launch_bounds__(256) void prep_kernel(const float* __restrict__ hs,
                                                   const float* __restrict__ m,
                                                   float* __restrict__ gridf,
                                                   short* __restrict__ xw) {
  int idx = blockIdx.x * 256 + threadIdx.x;
  if (idx >= 32 * 900 * 128) return;
  int c4 = idx & 127;
  int row = idx >> 7;
  int b = row / 900, rem = row % 900;
  int gy = rem / 30, gx = rem % 30;
  f32x4 v = *(const f32x4*)(hs + ((size_t)b * 916 + 16 + rem) * 512 + c4 * 4);
  f32x4 mm = *(const f32x4*)(m + b * 512 + c4 * 4);
  v += mm;
  *(f32x4*)(gridf + (size_t)row * 512 + c4 * 4) = v;
  int ry = gy + 29; if (ry >= 30) ry -= 30;
  int rx = gx + 29; if (rx >= 30) rx -= 30;
  int wi = ry / 3, ii = ry % 3, wj = rx / 3, jj = rx % 3;
  size_t xrow = (size_t)((b * 100 + wi * 10 + wj) * 9 + ii * 3 + jj);
  s16x4 o;
#pragma unroll
  for (int e = 0; e < 4; ++e) o[e] = f2bf(v[e]);
  *(s16x4*)(xw + xrow * 512 + c4 * 4) = o;
}

// ---------------- windowed attention (9 tokens, 8 heads per window) ----------
__global__ __launch_bounds__(256) void attn_kernel(const short* __restrict__ qkv,
                                                   const float* __restrict__ rel_bias,
                                                   short* __restrict__ outp) {
  __shared__ short sq[9 * 512];
  __shared__ short sk[9 * 512];
  __shared__ short sv[9 * 512];
  __shared__ float sS[648];
  const int wlin = blockIdx.x;
  const int w = wlin % 100;
  const int wi = w / 10, wj = w % 10;
  const int tid = threadIdx.x;
  const short* base = qkv + (size_t)wlin * 9 * 1536;
  for (int idx = tid; idx < 1728; idx += 256) {
    int n = idx / 192, c8 = idx % 192;
    s16x8 v = *(const s16x8*)(base + (size_t)n * 1536 + c8 * 8);
    int which = c8 >> 6;
    short* dst = (which == 0) ? sq : (which == 1) ? sk : sv;
    *(s16x8*)(dst + n * 512 + (c8 & 63) * 8) = v;
  }
  __syncthreads();
  for (int idx = tid; idx < 648; idx += 256) {
    int h = idx / 81, r = idx % 81, i = r / 9, j = r % 9;
    const short* qp = sq + i * 512 + h * 64;
    const short* kp = sk + j * 512 + h * 64;
    float dot = 0.f;
#pragma unroll
    for (int c = 0; c < 8; ++c) {
      s16x8 qv = *(const s16x8*)(qp + c * 8);
      s16x8 kv = *(const s16x8*)(kp + c * 8);
#pragma unroll
      for (int e = 0; e < 8; ++e) dot += bf2f(qv[e]) * bf2f(kv[e]);
    }
    float s = dot * 0.125f;
    int ia = i / 3, ja = i % 3, ib = j / 3, jb = j % 3;
    s += rel_bias[(5 * (ia - ib + 2) + (ja - jb + 2)) * 8 + h];
    int ra = wi * 3 + ia, ca = wj * 3 + ja, rb = wi * 3 + ib, cb = wj * 3 + jb;
    int rga = (ra < 27) ? 0 : (ra < 29) ? 1 : 2;
    int cga = (ca < 27) ? 0 : (ca < 29) ? 1 : 2;
    int rgb = (rb < 27) ? 0 : (rb < 29) ? 1 : 2;
    int cgb = (cb < 27) ? 0 : (cb < 29) ? 1 : 2;
    if (rga * 3 + cga != rgb * 3 + cgb) s -= 100.f;
    sS[idx] = s;
  }
  __syncthreads();
  if (tid < 72) {
    float* row = sS + tid * 9;
    float mx = row[0];
#pragma unroll
    for (int j = 1; j < 9; ++j) mx = fmaxf(mx, row[j]);
    float e[9], sum = 0.f;
#pragma unroll
    for (int j = 0; j < 9; ++j) { e[j] = __expf(row[j] - mx); sum += e[j]; }
    float inv = 1.f / sum;
#pragma unroll
    for (int j = 0; j < 9; ++j) row[j] = e[j] * inv;
  }
  __syncthreads();
  for (int idx = tid; idx < 576; idx += 256) {
    int h = idx / 72, r = idx % 72, i = r / 8, d8 = r % 8;
    const float* p = sS + (h * 9 + i) * 9;
    float a[8] = {0, 0, 0, 0, 0, 0, 0, 0};
#pragma unroll
    for (int j = 0; j < 9; ++j) {
      float pj = p[j];
      s16x8 vv = *(const s16x8*)(sv + j * 512 + h * 64 + d8 * 8);
#pragma unroll
      for (int e = 0; e < 8; ++e) a[e] += pj * bf2f(vv[e]);
    }
    s16x8 o;
#pragma unroll
    for (int e = 0; e < 8; ++e) o[e] = f2bf(a[e]);
    *(s16x8*)(outp + ((size_t)wlin * 9 + i) * 512 + h * 64 + d8 * 8) = o;
  }
}

// ---------------- add + RMS norm variants (one wave per row of 512) ---------
__global__ __launch_bounds__(64) void addnorm1_kernel(const float* __restrict__ g,
                                                      const short* __restrict__ p,
                                                      float* __restrict__ out,
                                                      short* __restrict__ hsb) {
  int row = blockIdx.x, lane = threadIdx.x;
  size_t off = (size_t)row * 512;
  f32x4 x[2];
  float ss = 0.f;
#pragma unroll
  for (int i = 0; i < 2; ++i) {
    f32x4 a = *(const f32x4*)(g + off + i * 256 + lane * 4);
    s16x4 b = *(const s16x4*)(p + off + i * 256 + lane * 4);
#pragma unroll
    for (int e = 0; e < 4; ++e) a[e] += bf2f(b[e]);
    x[i] = a;
    ss += a[0] * a[0] + a[1] * a[1] + a[2] * a[2] + a[3] * a[3];
  }
  ss = wave_allsum(ss);
  float sc = rsqrtf(ss * (1.f / 512.f) + 1e-5f);
  int b_ = row / 900, t = row % 900;
  size_t orow = ((size_t)b_ * 916 + 16 + t) * 512;
#pragma unroll
  for (int i = 0; i < 2; ++i) {
    f32x4 y = x[i] * sc;
    *(f32x4*)(out + orow + i * 256 + lane * 4) = y;
    s16x4 o;
#pragma unroll
    for (int e = 0; e < 4; ++e) o[e] = f2bf(y[e]);
    *(s16x4*)(hsb + orow + i * 256 + lane * 4) = o;
  }
}

__global__ __launch_bounds__(64) void prefix_addnorm_kernel(const float* __restrict__ hs,
                                                            const short* __restrict__ pd,
                                                            float* __restrict__ out,
                                                            short* __restrict__ hsb) {
  int r = blockIdx.x, lane = threadIdx.x;
  int b = r >> 4, t = r & 15;
  size_t orow = ((size_t)b * 916 + t) * 512;
  f32x4 x[2];
  float ss = 0.f;
#pragma unroll
  for (int i = 0; i < 2; ++i) {
    f32x4 a = *(const f32x4*)(hs + orow + i * 256 + lane * 4);
    s16x4 d = *(const s16x4*)(pd + (size_t)r * 512 + i * 256 + lane * 4);
#pragma unroll
    for (int e = 0; e < 4; ++e) a[e] += bf2f(d[e]);
    x[i] = a;
    ss += a[0] * a[0] + a[1] * a[1] + a[2] * a[2] + a[3] * a[3];
  }
  ss = wave_allsum(ss);
  float sc = rsqrtf(ss * (1.f / 512.f) + 1e-5f);
#pragma unroll
  for (int i = 0; i < 2; ++i) {
    f32x4 y = x[i] * sc;
    *(f32x4*)(out + orow + i * 256 + lane * 4) = y;
    s16x4 o;
#pragma unroll
    for (int e = 0; e < 4; ++e) o[e] = f2bf(y[e]);
    *(s16x4*)(hsb + orow + i * 256 + lane * 4) = o;
  }
}

// in-place: io holds hs + down-proj sum; normalize each row
__global__ __launch_bounds__(64) void final_addnorm_kernel(float* __restrict__ io) {
  int row = blockIdx.x, lane = threadIdx.x;
  size_t off = (size_t)row * 512;
  f32x4 x[2];
  float ss = 0.f;
#pragma unroll
  for (int i = 0; i < 2; ++i) {
    f32x4 a = *(const f32x4*)(io + off + i * 256 + lane * 4);
    x[i] = a;
    ss += a[0] * a[0] + a[1] * a[1] + a[2] * a[2] + a[3] * a[3];
  }
  ss = wave_allsum(ss);
  float sc = rsqrtf(ss * (1.f / 512.f) + 1e-5f);
#pragma unroll
  for (int i = 0; i < 2; ++i)
    *(f32x4*)(io + off + i * 256 + lane * 4) = x[i] * sc;
}

// ---------------- workspace layout (bytes; liveness-overlaid) ----------------
// ws proven >= 226.9 MB (R1 passing layout). No same-kernel src/dst overlaps.
static constexpr size_t OFF_WQKV   = 0;                       // 3*512*512*2
static constexpr size_t OFF_WPROJ  = 1572864;                 // 512*512*2
static constexpr size_t OFF_WGU    = 2097152;                 // 3072*512*2
static constexpr size_t OFF_WDOWN  = 5242880;                 // 512*1536*2
static constexpr size_t OFF_WPGU   = 6815744;                 // 3072*512*2
static constexpr size_t OFF_WPDOWN = 9961472;                 // 512*1536*2
static constexpr size_t OFF_MEAN   = 11534336;                // 32*512*4
static constexpr size_t OFF_PREFB  = 11599872;                // 512*512*2
static constexpr size_t OFF_PINTER = 13697024;                // 512*1536*2
static constexpr size_t OFF_PDOUT  = 15269888;                // 512*512*2
static constexpr size_t OFF_GRIDF  = 16777216;                // 28800*512*4 -> 75759616
static constexpr size_t OFF_XW     = 75759616;                // 28800*512*2 -> 105250816
static constexpr size_t OFF_QKV    = 105250816;               // 28800*1536*2 -> 193724416
static constexpr size_t OFF_ATTNO  = OFF_XW;                  // reuse (xw dead after QKV gemm)
static constexpr size_t OFF_PROJS  = OFF_QKV;                 // reuse (qkvb dead after attn)
static constexpr size_t OFF_INTER  = OFF_GRIDF;               // reuse (gridf dead after addnorm1)
static constexpr size_t OFF_HSB    = 193724416;               // 29312*512*2 -> 223739904
// dnout eliminated: down-GEMM adds into d_out (fp32) directly.

extern "C" void kernel_launch(void* const* d_in, const int* in_sizes, int n_in,
                              void* d_out, int out_size, void* d_ws, size_t ws_size,
                              hipStream_t stream) {
  const float* hs      = (const float*)d_in[0];
  const float* qkv_w   = (const float*)d_in[1];
  const float* qkv_b   = (const float*)d_in[2];
  const float* proj_w  = (const float*)d_in[3];
  const float* proj_b  = (const float*)d_in[4];
  const float* rel_b   = (const float*)d_in[5];
  const float* gu_w    = (const float*)d_in[6];
  const float* down_w  = (const float*)d_in[7];
  const float* pgu_w   = (const float*)d_in[8];
  const float* pdown_w = (const float*)d_in[9];

  char* ws = (char*)d_ws;
  short* Wqkv   = (short*)(ws + OFF_WQKV);
  short* Wproj  = (short*)(ws + OFF_WPROJ);
  short* Wgu    = (short*)(ws + OFF_WGU);
  short* Wdown  = (short*)(ws + OFF_WDOWN);
  short* Wpgu   = (short*)(ws + OFF_WPGU);
  short* Wpdown = (short*)(ws + OFF_WPDOWN);
  float* meanb  = (float*)(ws + OFF_MEAN);
  short* prefb  = (short*)(ws + OFF_PREFB);
  short* pinter = (short*)(ws + OFF_PINTER);
  short* pdout  = (short*)(ws + OFF_PDOUT);
  float* gridf  = (float*)(ws + OFF_GRIDF);
  short* xw     = (short*)(ws + OFF_XW);
  short* qkvb   = (short*)(ws + OFF_QKV);
  short* attno  = (short*)(ws + OFF_ATTNO);
  short* projs  = (short*)(ws + OFF_PROJS);
  short* interb = (short*)(ws + OFF_INTER);
  short* hsb    = (short*)(ws + OFF_HSB);
  float* outf   = (float*)d_out;

  // 1. weight fp32 -> bf16
  cvt4_kernel<<<768, 256, 0, stream>>>(qkv_w, Wqkv, 786432 / 4);
  cvt4_kernel<<<256, 256, 0, stream>>>(proj_w, Wproj, 262144 / 4);
  cvt4_kernel<<<1536, 256, 0, stream>>>(gu_w, Wgu, 1572864 / 4);
  cvt4_kernel<<<768, 256, 0, stream>>>(down_w, Wdown, 786432 / 4);
  cvt4_kernel<<<1536, 256, 0, stream>>>(pgu_w, Wpgu, 1572864 / 4);
  cvt4_kernel<<<768, 256, 0, stream>>>(pdown_w, Wpdown, 786432 / 4);
  prefix_cvt_kernel<<<256, 256, 0, stream>>>(hs, prefb);

  // 2. prefix mean -> grid residual + rolled/window-partitioned bf16
  mean_kernel<<<32, 512, 0, stream>>>(hs, meanb);
  prep_kernel<<<14400, 256, 0, stream>>>(hs, meanb, gridf, xw);

  // 3. QKV projection (M=28800, N=1536, K=512), +bias, bf16 out
  gemm_bt<EPI_BIAS_BF16><<<dim3(12, 225), 256, 0, stream>>>(xw, Wqkv, qkv_b, qkvb,
                                                            28800, 1536, 512);
  // 4. windowed attention
  attn_kernel<<<3200, 256, 0, stream>>>(qkvb, rel_b, attno);

  // 5. output projection, scatter to un-windowed un-rolled bf16 layout
  gemm_bt<EPI_SCATTER><<<dim3(4, 225), 256, 0, stream>>>(attno, Wproj, proj_b, projs,
                                                         28800, 512, 512);
  // 6. x = rms(residual + proj) -> fp32 rows of d_out + bf16 hsb
  addnorm1_kernel<<<28800, 64, 0, stream>>>(gridf, projs, outf, hsb);

  // 7. prefix branch: fused swiglu + rms
  gemm_gu<<<dim3(12, 4), 256, 0, stream>>>(prefb, Wpgu, Wpgu + 1536 * 512, pinter,
                                           512, 512);
  gemm_bt<EPI_BF16><<<dim3(4, 4), 256, 0, stream>>>(pinter, Wpdown, nullptr, pdout,
                                                    512, 512, 1536);
  prefix_addnorm_kernel<<<512, 64, 0, stream>>>(hs, pdout, outf, hsb);

  // 8. full-sequence fused swiglu (M=29312); down-proj adds into d_out fp32
  gemm_gu<<<dim3(12, 229), 256, 0, stream>>>(hsb, Wgu, Wgu + 1536 * 512, interb,
                                             29312, 512);
  gemm_bt<EPI_ADDOUT><<<dim3(4, 229), 256, 0, stream>>>(interb, Wdown, nullptr, outf,
                                                        29312, 512, 1536);
  // 9. out = rms(out) in place
  final_addnorm_kernel<<<29312, 64, 0, stream>>>(outf);

  (void)in_sizes; (void)n_in; (void)out_size; (void)ws_size;
}

// Round 4
// 495.288 us; speedup vs baseline: 1.1604x; 1.1604x over previous
//
#include <hip/hip_runtime.h>
#include <cstdint>
#include <cstddef>

typedef float f32x4 __attribute__((ext_vector_type(4)));
typedef short s16x8 __attribute__((ext_vector_type(8)));
typedef short s16x4 __attribute__((ext_vector_type(4)));

#define DEV static __device__ __forceinline__

DEV float bf2f(short s) {
  union { unsigned u; float f; } c;
  c.u = ((unsigned)(unsigned short)s) << 16;
  return c.f;
}
DEV short f2bf(float f) {
  union { float f; unsigned u; } c;
  c.f = f;
  unsigned r = c.u + 0x7fffu + ((c.u >> 16) & 1u);
  return (short)(r >> 16);
}
DEV float wave_allsum(float v) {
#pragma unroll
  for (int off = 32; off > 0; off >>= 1) v += __shfl_xor(v, off, 64);
  return v;
}
DEV void gload_lds16(const void* g, void* l) {
  __builtin_amdgcn_global_load_lds(
      (const __attribute__((address_space(1))) void*)g,
      (__attribute__((address_space(3))) void*)l, 16, 0, 0);
}
DEV float silu_f(float g) { return g / (1.f + __expf(-g)); }

// bijective XCD-chunk swizzle (m204)
DEV int xcd_swizzle(int orig, int nwg) {
  int q = nwg >> 3, r = nwg & 7;
  int xcd = orig & 7, pos = orig >> 3;
  return (xcd < r ? xcd * (q + 1) : r * (q + 1) + (xcd - r) * q) + pos;
}

DEV void sync_phase() {
  asm volatile("s_waitcnt vmcnt(0)" ::: "memory");
  __builtin_amdgcn_s_barrier();
  __builtin_amdgcn_sched_barrier(0);
}

// ---------------- 2-phase double-buffered bf16 GEMM ----------------
// C = A(MxK) @ W(NxK)^T. 128x128 tile (EPI_GU: 128x64 with B rows 0-63=Wg,
// 64-127=Wu), BK=64, 4 waves, global_load_lds(16B), XOR k-group swizzle.
// T3-minimum schedule: stage(next) BEFORE compute(cur); one vmcnt(0)+s_barrier
// AFTER compute -> next-tile loads hide under MFMA. Buffers are distinct
// __shared__ arrays + even/odd unroll so all indices are compile-time (alias
// analysis can't force an early drain).
enum { EPI_BF16 = 0, EPI_BIAS_BF16 = 1, EPI_SCATTER = 4, EPI_ADDOUT = 5, EPI_GU = 6 };

template <int EPI>
__global__ __launch_bounds__(256) void gemm2(
    const short* __restrict__ A, const short* __restrict__ W,
    const short* __restrict__ Wu, const float* __restrict__ bias,
    void* __restrict__ outp, int M, int N, int K)
{
  __shared__ short As0[8192], Bs0[8192];
  __shared__ short As1[8192], Bs1[8192];
  const int tid = threadIdx.x;
  const int wave = tid >> 6, lane = tid & 63;
  const int nwg = gridDim.x * gridDim.y;
  const int orig = blockIdx.y * gridDim.x + blockIdx.x;
  const int wg = xcd_swizzle(orig, nwg);
  const int bx = wg % gridDim.x, by = wg / gridDim.x;
  const int row0 = by * 128;
  const int col0 = (EPI == EPI_GU) ? bx * 64 : bx * 128;
  const int wr = wave >> 1, wc = wave & 1;

  f32x4 acc[4][4];
#pragma unroll
  for (int m = 0; m < 4; ++m)
#pragma unroll
    for (int n = 0; n < 4; ++n) acc[m][n] = f32x4{0.f, 0.f, 0.f, 0.f};

  // staging geometry: issue i covers LDS elements [i*2048 + tid*8, +8)
  const short* aptr[4];
  const short* bptr[4];
  int ldst[4];
#pragma unroll
  for (int i = 0; i < 4; ++i) {
    int e = i * 2048 + tid * 8;
    int srow = e >> 6;
    int skg = ((e >> 3) & 7) ^ (srow & 7);
    aptr[i] = A + (size_t)(row0 + srow) * K + skg * 8;
    if (EPI == EPI_GU)
      bptr[i] = (srow < 64 ? W + (size_t)(col0 + srow) * K
                           : Wu + (size_t)(col0 + srow - 64) * K) + skg * 8;
    else
      bptr[i] = W + (size_t)(col0 + srow) * K + skg * 8;
    ldst[i] = i * 2048 + wave * 512;
  }

#define STAGE(AS, BS, KT)                                   \
  do {                                                      \
    _Pragma("unroll") for (int i = 0; i < 4; ++i)           \
        gload_lds16(aptr[i] + (KT), &AS[ldst[i]]);          \
    _Pragma("unroll") for (int i = 0; i < 4; ++i)           \
        gload_lds16(bptr[i] + (KT), &BS[ldst[i]]);          \
  } while (0)

#define COMPUTE(AS, BS)                                                        \
  do {                                                                         \
    _Pragma("unroll") for (int ks = 0; ks < 2; ++ks) {                         \
      s16x8 af[4], bfr[4];                                                     \
      _Pragma("unroll") for (int m = 0; m < 4; ++m) {                          \
        int row = wr * 64 + m * 16 + (lane & 15);                              \
        int kg = (ks * 4 + (lane >> 4)) ^ (row & 7);                           \
        af[m] = *(const s16x8*)&AS[row * 64 + kg * 8];                         \
      }                                                                        \
      _Pragma("unroll") for (int n = 0; n < 4; ++n) {                          \
        int brow = (EPI == EPI_GU)                                             \
                       ? ((n < 2 ? wc * 32 + n * 16                            \
                                 : 64 + wc * 32 + (n - 2) * 16) + (lane & 15)) \
                       : (wc * 64 + n * 16 + (lane & 15));                     \
        int kg = (ks * 4 + (lane >> 4)) ^ (brow & 7);                          \
        bfr[n] = *(const s16x8*)&BS[brow * 64 + kg * 8];                       \
      }                                                                        \
      _Pragma("unroll") for (int m = 0; m < 4; ++m)                            \
          _Pragma("unroll") for (int n = 0; n < 4; ++n)                        \
              acc[m][n] = __builtin_amdgcn_mfma_f32_16x16x32_bf16(             \
                  af[m], bfr[n], acc[m][n], 0, 0, 0);                          \
    }                                                                          \
  } while (0)

  // prologue
  STAGE(As0, Bs0, 0);
  sync_phase();
  // main loop: K % 128 == 0 for all call sites (512, 1536)
  for (int kt = 0; kt < K; kt += 128) {
    STAGE(As1, Bs1, kt + 64);
    COMPUTE(As0, Bs0);
    sync_phase();
    if (kt + 128 < K) STAGE(As0, Bs0, kt + 128);
    COMPUTE(As1, Bs1);
    if (kt + 128 < K) sync_phase();
  }
#undef STAGE
#undef COMPUTE

  const int lr = (lane >> 4) * 4, lc = lane & 15;
#pragma unroll
  for (int m = 0; m < 4; ++m) {
#pragma unroll
    for (int i = 0; i < 4; ++i) {
      int gr = row0 + wr * 64 + m * 16 + lr + i;
      size_t orow;
      if (EPI == EPI_SCATTER) {
        int b = gr / 900, rem = gr % 900;
        int w = rem / 9, n_ = rem % 9;
        int wi = w / 10, wj = w % 10;
        int ii = n_ / 3, jj = n_ % 3;
        int gy = wi * 3 + ii + 1; if (gy >= 30) gy -= 30;
        int gx = wj * 3 + jj + 1; if (gx >= 30) gx -= 30;
        orow = (size_t)b * 900 + gy * 30 + gx;
      } else {
        orow = (size_t)gr;
      }
      if (EPI == EPI_GU) {
#pragma unroll
        for (int n = 0; n < 2; ++n) {
          int gc = col0 + wc * 32 + n * 16 + lc;
          float v = silu_f(acc[m][n][i]) * acc[m][n + 2][i];
          ((short*)outp)[orow * (size_t)N + gc] = f2bf(v);
        }
      } else {
#pragma unroll
        for (int n = 0; n < 4; ++n) {
          int gc = col0 + wc * 64 + n * 16 + lc;
          float v = acc[m][n][i];
          if (EPI == EPI_BIAS_BF16 || EPI == EPI_SCATTER) v += bias[gc];
          if (EPI == EPI_ADDOUT) {
            float* po = (float*)outp;
            size_t oi = orow * (size_t)N + gc;
            po[oi] = po[oi] + v;  // each output element owned by exactly one block
          } else {
            ((short*)outp)[orow * (size_t)N + gc] = f2bf(v);
          }
        }
      }
    }
  }
}

// ---------------- weight / activation conversion ----------------
__global__ __launch_bounds__(256) void cvt4_kernel(const float* __restrict__ src,
                                                   short* __restrict__ dst, int n4) {
  int i = blockIdx.x * 256 + threadIdx.x;
  if (i >= n4) return;
  f32x4 v = *(const f32x4*)(src + (size_t)i * 4);
  s16x4 o;
#pragma unroll
  for (int e = 0; e < 4; ++e) o[e] = f2bf(v[e]);
  *(s16x4*)(dst + (size_t)i * 4) = o;
}

__global__ __launch_bounds__(256) void prefix_cvt_kernel(const float* __restrict__ hs,
                                                         short* __restrict__ dst) {
  int i = blockIdx.x * 256 + threadIdx.x;
  if (i >= 512 * 128) return;
  int r = i >> 7, c4 = i & 127;
  int b = r >> 4, t = r & 15;
  f32x4 v = *(const f32x4*)(hs + ((size_t)b * 916 + t) * 512 + c4 * 4);
  s16x4 o;
#pragma unroll
  for (int e = 0; e < 4; ++e) o[e] = f2bf(v[e]);
  *(s16x4*)(dst + (size_t)r * 512 + c4 * 4) = o;
}

__global__ __launch_bounds__(512) void mean_kernel(const float* __restrict__ hs,
                                                   float* __restrict__ m) {
  int b = blockIdx.x, d = threadIdx.x;
  float s = 0.f;
#pragma unroll
  for (int t = 0; t < 16; ++t) s += hs[((size_t)b * 916 + t) * 512 + d];
  m[b * 512 + d] = s * (1.f / 16.f);
}

__global__ __launch_bounds__(256) void prep_kernel(const float* __restrict__ hs,
                                                   const float* __restrict__ m,
                                                   float* __restrict__ gridf,
                                                   short* __restrict__ xw) {
  int idx = blockIdx.x * 256 + threadIdx.x;
  if (idx >= 32 * 900 * 128) return;
  int c4 = idx & 127;
  int row = idx >> 7;
  int b = row / 900, rem = row % 900;
  int gy = rem / 30, gx = rem % 30;
  f32x4 v = *(const f32x4*)(hs + ((size_t)b * 916 + 16 + rem) * 512 + c4 * 4);
  f32x4 mm = *(const f32x4*)(m + b * 512 + c4 * 4);
  v += mm;
  *(f32x4*)(gridf + (size_t)row * 512 + c4 * 4) = v;
  int ry = gy + 29; if (ry >= 30) ry -= 30;
  int rx = gx + 29; if (rx >= 30) rx -= 30;
  int wi = ry / 3, ii = ry % 3, wj = rx / 3, jj = rx % 3;
  size_t xrow = (size_t)((b * 100 + wi * 10 + wj) * 9 + ii * 3 + jj);
  s16x4 o;
#pragma unroll
  for (int e = 0; e < 4; ++e) o[e] = f2bf(v[e]);
  *(s16x4*)(xw + xrow * 512 + c4 * 4) = o;
}

// ---------------- windowed attention (9 tokens, 8 heads per window) ----------
__global__ __launch_bounds__(256) void attn_kernel(const short* __restrict__ qkv,
                                                   const float* __restrict__ rel_bias,
                                                   short* __restrict__ outp) {
  __shared__ short sq[9 * 512];
  __shared__ short sk[9 * 512];
  __shared__ short sv[9 * 512];
  __shared__ float sS[648];
  const int wlin = blockIdx.x;
  const int w = wlin % 100;
  const int wi = w / 10, wj = w % 10;
  const int tid = threadIdx.x;
  const short* base = qkv + (size_t)wlin * 9 * 1536;
  for (int idx = tid; idx < 1728; idx += 256) {
    int n = idx / 192, c8 = idx % 192;
    s16x8 v = *(const s16x8*)(base + (size_t)n * 1536 + c8 * 8);
    int which = c8 >> 6;
    short* dst = (which == 0) ? sq : (which == 1) ? sk : sv;
    *(s16x8*)(dst + n * 512 + (c8 & 63) * 8) = v;
  }
  __syncthreads();
  for (int idx = tid; idx < 648; idx += 256) {
    int h = idx / 81, r = idx % 81, i = r / 9, j = r % 9;
    const short* qp = sq + i * 512 + h * 64;
    const short* kp = sk + j * 512 + h * 64;
    float dot = 0.f;
#pragma unroll
    for (int c = 0; c < 8; ++c) {
      s16x8 qv = *(const s16x8*)(qp + c * 8);
      s16x8 kv = *(const s16x8*)(kp + c * 8);
#pragma unroll
      for (int e = 0; e < 8; ++e) dot += bf2f(qv[e]) * bf2f(kv[e]);
    }
    float s = dot * 0.125f;
    int ia = i / 3, ja = i % 3, ib = j / 3, jb = j % 3;
    s += rel_bias[(5 * (ia - ib + 2) + (ja - jb + 2)) * 8 + h];
    int ra = wi * 3 + ia, ca = wj * 3 + ja, rb = wi * 3 + ib, cb = wj * 3 + jb;
    int rga = (ra < 27) ? 0 : (ra < 29) ? 1 : 2;
    int cga = (ca < 27) ? 0 : (ca < 29) ? 1 : 2;
    int rgb = (rb < 27) ? 0 : (rb < 29) ? 1 : 2;
    int cgb = (cb < 27) ? 0 : (cb < 29) ? 1 : 2;
    if (rga * 3 + cga != rgb * 3 + cgb) s -= 100.f;
    sS[idx] = s;
  }
  __syncthreads();
  if (tid < 72) {
    float* row = sS + tid * 9;
    float mx = row[0];
#pragma unroll
    for (int j = 1; j < 9; ++j) mx = fmaxf(mx, row[j]);
    float e[9], sum = 0.f;
#pragma unroll
    for (int j = 0; j < 9; ++j) { e[j] = __expf(row[j] - mx); sum += e[j]; }
    float inv = 1.f / sum;
#pragma unroll
    for (int j = 0; j < 9; ++j) row[j] = e[j] * inv;
  }
  __syncthreads();
  for (int idx = tid; idx < 576; idx += 256) {
    int h = idx / 72, r = idx % 72, i = r / 8, d8 = r % 8;
    const float* p = sS + (h * 9 + i) * 9;
    float a[8] = {0, 0, 0, 0, 0, 0, 0, 0};
#pragma unroll
    for (int j = 0; j < 9; ++j) {
      float pj = p[j];
      s16x8 vv = *(const s16x8*)(sv + j * 512 + h * 64 + d8 * 8);
#pragma unroll
      for (int e = 0; e < 8; ++e) a[e] += pj * bf2f(vv[e]);
    }
    s16x8 o;
#pragma unroll
    for (int e = 0; e < 8; ++e) o[e] = f2bf(a[e]);
    *(s16x8*)(outp + ((size_t)wlin * 9 + i) * 512 + h * 64 + d8 * 8) = o;
  }
}

// ---------------- add + RMS norm variants (one wave per row of 512) ---------
__global__ __launch_bounds__(64) void addnorm1_kernel(const float* __restrict__ g,
                                                      const short* __restrict__ p,
                                                      float* __restrict__ out,
                                                      short* __restrict__ hsb) {
  int row = blockIdx.x, lane = threadIdx.x;
  size_t off = (size_t)row * 512;
  f32x4 x[2];
  float ss = 0.f;
#pragma unroll
  for (int i = 0; i < 2; ++i) {
    f32x4 a = *(const f32x4*)(g + off + i * 256 + lane * 4);
    s16x4 b = *(const s16x4*)(p + off + i * 256 + lane * 4);
#pragma unroll
    for (int e = 0; e < 4; ++e) a[e] += bf2f(b[e]);
    x[i] = a;
    ss += a[0] * a[0] + a[1] * a[1] + a[2] * a[2] + a[3] * a[3];
  }
  ss = wave_allsum(ss);
  float sc = rsqrtf(ss * (1.f / 512.f) + 1e-5f);
  int b_ = row / 900, t = row % 900;
  size_t orow = ((size_t)b_ * 916 + 16 + t) * 512;
#pragma unroll
  for (int i = 0; i < 2; ++i) {
    f32x4 y = x[i] * sc;
    *(f32x4*)(out + orow + i * 256 + lane * 4) = y;
    s16x4 o;
#pragma unroll
    for (int e = 0; e < 4; ++e) o[e] = f2bf(y[e]);
    *(s16x4*)(hsb + orow + i * 256 + lane * 4) = o;
  }
}

__global__ __launch_bounds__(64) void prefix_addnorm_kernel(const float* __restrict__ hs,
                                                            const short* __restrict__ pd,
                                                            float* __restrict__ out,
                                                            short* __restrict__ hsb) {
  int r = blockIdx.x, lane = threadIdx.x;
  int b = r >> 4, t = r & 15;
  size_t orow = ((size_t)b * 916 + t) * 512;
  f32x4 x[2];
  float ss = 0.f;
#pragma unroll
  for (int i = 0; i < 2; ++i) {
    f32x4 a = *(const f32x4*)(hs + orow + i * 256 + lane * 4);
    s16x4 d = *(const s16x4*)(pd + (size_t)r * 512 + i * 256 + lane * 4);
#pragma unroll
    for (int e = 0; e < 4; ++e) a[e] += bf2f(d[e]);
    x[i] = a;
    ss += a[0] * a[0] + a[1] * a[1] + a[2] * a[2] + a[3] * a[3];
  }
  ss = wave_allsum(ss);
  float sc = rsqrtf(ss * (1.f / 512.f) + 1e-5f);
#pragma unroll
  for (int i = 0; i < 2; ++i) {
    f32x4 y = x[i] * sc;
    *(f32x4*)(out + orow + i * 256 + lane * 4) = y;
    s16x4 o;
#pragma unroll
    for (int e = 0; e < 4; ++e) o[e] = f2bf(y[e]);
    *(s16x4*)(hsb + orow + i * 256 + lane * 4) = o;
  }
}

// in-place: io holds hs + down-proj sum; normalize each row
__global__ __launch_bounds__(64) void final_addnorm_kernel(float* __restrict__ io) {
  int row = blockIdx.x, lane = threadIdx.x;
  size_t off = (size_t)row * 512;
  f32x4 x[2];
  float ss = 0.f;
#pragma unroll
  for (int i = 0; i < 2; ++i) {
    f32x4 a = *(const f32x4*)(io + off + i * 256 + lane * 4);
    x[i] = a;
    ss += a[0] * a[0] + a[1] * a[1] + a[2] * a[2] + a[3] * a[3];
  }
  ss = wave_allsum(ss);
  float sc = rsqrtf(ss * (1.f / 512.f) + 1e-5f);
#pragma unroll
  for (int i = 0; i < 2; ++i)
    *(f32x4*)(io + off + i * 256 + lane * 4) = x[i] * sc;
}

// ---------------- workspace layout (bytes; liveness-overlaid) ----------------
// ws proven >= 226.9 MB (R1/R3 passing layouts). No same-kernel src/dst overlaps.
static constexpr size_t OFF_WQKV   = 0;                       // 3*512*512*2
static constexpr size_t OFF_WPROJ  = 1572864;                 // 512*512*2
static constexpr size_t OFF_WGU    = 2097152;                 // 3072*512*2
static constexpr size_t OFF_WDOWN  = 5242880;                 // 512*1536*2
static constexpr size_t OFF_WPGU   = 6815744;                 // 3072*512*2
static constexpr size_t OFF_WPDOWN = 9961472;                 // 512*1536*2
static constexpr size_t OFF_MEAN   = 11534336;                // 32*512*4
static constexpr size_t OFF_PREFB  = 11599872;                // 512*512*2
static constexpr size_t OFF_PINTER = 13697024;                // 512*1536*2
static constexpr size_t OFF_PDOUT  = 15269888;                // 512*512*2
static constexpr size_t OFF_GRIDF  = 16777216;                // 28800*512*4 -> 75759616
static constexpr size_t OFF_XW     = 75759616;                // 28800*512*2 -> 105250816
static constexpr size_t OFF_QKV    = 105250816;               // 28800*1536*2 -> 193724416
static constexpr size_t OFF_ATTNO  = OFF_XW;                  // reuse (xw dead after QKV gemm)
static constexpr size_t OFF_PROJS  = OFF_QKV;                 // reuse (qkvb dead after attn)
static constexpr size_t OFF_INTER  = OFF_GRIDF;               // reuse (gridf dead after addnorm1)
static constexpr size_t OFF_HSB    = 193724416;               // 29312*512*2 -> 223739904

extern "C" void kernel_launch(void* const* d_in, const int* in_sizes, int n_in,
                              void* d_out, int out_size, void* d_ws, size_t ws_size,
                              hipStream_t stream) {
  const float* hs      = (const float*)d_in[0];
  const float* qkv_w   = (const float*)d_in[1];
  const float* qkv_b   = (const float*)d_in[2];
  const float* proj_w  = (const float*)d_in[3];
  const float* proj_b  = (const float*)d_in[4];
  const float* rel_b   = (const float*)d_in[5];
  const float* gu_w    = (const float*)d_in[6];
  const float* down_w  = (const float*)d_in[7];
  const float* pgu_w   = (const float*)d_in[8];
  const float* pdown_w = (const float*)d_in[9];

  char* ws = (char*)d_ws;
  short* Wqkv   = (short*)(ws + OFF_WQKV);
  short* Wproj  = (short*)(ws + OFF_WPROJ);
  short* Wgu    = (short*)(ws + OFF_WGU);
  short* Wdown  = (short*)(ws + OFF_WDOWN);
  short* Wpgu   = (short*)(ws + OFF_WPGU);
  short* Wpdown = (short*)(ws + OFF_WPDOWN);
  float* meanb  = (float*)(ws + OFF_MEAN);
  short* prefb  = (short*)(ws + OFF_PREFB);
  short* pinter = (short*)(ws + OFF_PINTER);
  short* pdout  = (short*)(ws + OFF_PDOUT);
  float* gridf  = (float*)(ws + OFF_GRIDF);
  short* xw     = (short*)(ws + OFF_XW);
  short* qkvb   = (short*)(ws + OFF_QKV);
  short* attno  = (short*)(ws + OFF_ATTNO);
  short* projs  = (short*)(ws + OFF_PROJS);
  short* interb = (short*)(ws + OFF_INTER);
  short* hsb    = (short*)(ws + OFF_HSB);
  float* outf   = (float*)d_out;

  // 1. weight fp32 -> bf16
  cvt4_kernel<<<768, 256, 0, stream>>>(qkv_w, Wqkv, 786432 / 4);
  cvt4_kernel<<<256, 256, 0, stream>>>(proj_w, Wproj, 262144 / 4);
  cvt4_kernel<<<1536, 256, 0, stream>>>(gu_w, Wgu, 1572864 / 4);
  cvt4_kernel<<<768, 256, 0, stream>>>(down_w, Wdown, 786432 / 4);
  cvt4_kernel<<<1536, 256, 0, stream>>>(pgu_w, Wpgu, 1572864 / 4);
  cvt4_kernel<<<768, 256, 0, stream>>>(pdown_w, Wpdown, 786432 / 4);
  prefix_cvt_kernel<<<256, 256, 0, stream>>>(hs, prefb);

  // 2. prefix mean -> grid residual + rolled/window-partitioned bf16
  mean_kernel<<<32, 512, 0, stream>>>(hs, meanb);
  prep_kernel<<<14400, 256, 0, stream>>>(hs, meanb, gridf, xw);

  // 3. QKV projection (M=28800, N=1536, K=512), +bias, bf16 out
  gemm2<EPI_BIAS_BF16><<<dim3(12, 225), 256, 0, stream>>>(
      xw, Wqkv, nullptr, qkv_b, qkvb, 28800, 1536, 512);
  // 4. windowed attention
  attn_kernel<<<3200, 256, 0, stream>>>(qkvb, rel_b, attno);

  // 5. output projection, scatter to un-windowed un-rolled bf16 layout
  gemm2<EPI_SCATTER><<<dim3(4, 225), 256, 0, stream>>>(
      attno, Wproj, nullptr, proj_b, projs, 28800, 512, 512);
  // 6. x = rms(residual + proj) -> fp32 rows of d_out + bf16 hsb
  addnorm1_kernel<<<28800, 64, 0, stream>>>(gridf, projs, outf, hsb);

  // 7. prefix branch: fused swiglu (BN=64 gu variant) + down + rms
  gemm2<EPI_GU><<<dim3(24, 4), 256, 0, stream>>>(
      prefb, Wpgu, Wpgu + 1536 * 512, nullptr, pinter, 512, 1536, 512);
  gemm2<EPI_BF16><<<dim3(4, 4), 256, 0, stream>>>(
      pinter, Wpdown, nullptr, nullptr, pdout, 512, 512, 1536);
  prefix_addnorm_kernel<<<512, 64, 0, stream>>>(hs, pdout, outf, hsb);

  // 8. full-sequence fused swiglu (M=29312); down-proj adds into d_out fp32
  gemm2<EPI_GU><<<dim3(24, 229), 256, 0, stream>>>(
      hsb, Wgu, Wgu + 1536 * 512, nullptr, interb, 29312, 1536, 512);
  gemm2<EPI_ADDOUT><<<dim3(4, 229), 256, 0, stream>>>(
      interb, Wdown, nullptr, nullptr, outf, 29312, 512, 1536);
  // 9. out = rms(out) in place
  final_addnorm_kernel<<<29312, 64, 0, stream>>>(outf);

  (void)in_sizes; (void)n_in; (void)out_size; (void)ws_size;
}

// Round 5
// 490.094 us; speedup vs baseline: 1.1726x; 1.0106x over previous
//
#include <hip/hip_runtime.h>
#include <cstdint>
#include <cstddef>

typedef float f32x4 __attribute__((ext_vector_type(4)));
typedef short s16x8 __attribute__((ext_vector_type(8)));
typedef short s16x4 __attribute__((ext_vector_type(4)));

#define DEV static __device__ __forceinline__

DEV float bf2f(short s) {
  union { unsigned u; float f; } c;
  c.u = ((unsigned)(unsigned short)s) << 16;
  return c.f;
}
DEV short f2bf(float f) {
  union { float f; unsigned u; } c;
  c.f = f;
  unsigned r = c.u + 0x7fffu + ((c.u >> 16) & 1u);
  return (short)(r >> 16);
}
DEV float wave_allsum(float v) {
#pragma unroll
  for (int off = 32; off > 0; off >>= 1) v += __shfl_xor(v, off, 64);
  return v;
}
DEV void gload_lds16(const void* g, void* l) {
  __builtin_amdgcn_global_load_lds(
      (const __attribute__((address_space(1))) void*)g,
      (__attribute__((address_space(3))) void*)l, 16, 0, 0);
}
DEV float silu_f(float g) { return g / (1.f + __expf(-g)); }

// bijective XCD-chunk swizzle (m204)
DEV int xcd_swizzle(int orig, int nwg) {
  int q = nwg >> 3, r = nwg & 7;
  int xcd = orig & 7, pos = orig >> 3;
  return (xcd < r ? xcd * (q + 1) : r * (q + 1) + (xcd - r) * q) + pos;
}

DEV void sync_phase() {
  asm volatile("s_waitcnt vmcnt(0)" ::: "memory");
  __builtin_amdgcn_s_barrier();
  __builtin_amdgcn_sched_barrier(0);
}

enum { EPI_BF16 = 0, EPI_BIAS_BF16 = 1, EPI_SCATTER = 4, EPI_ADDOUT = 5, EPI_GU = 6 };

// ================= 8-phase 256x256 bf16 GEMM (T3+T4+T5) =================
// C = A(MxK) @ W(NxK)^T. BK=64, 8 waves (2M x 4N), per-wave 128x64 out.
// LDS 128 KiB: A[2][256][64] + B[2][256][64], XOR k-group swizzle (linear
// LDS dest, inverse-swizzled global src, swizzled ds_read).
// Schedule per tile t (buf d), staging tile t+1 into dead buf d^1:
//   p0: SB units 0,1 | vmcnt(4)+barrier | read B-frags(regs)+A m0,m1 | 16 MFMA
//   p1: SB units 2,3 |                    read A m2,m3               | 16 MFMA
//   p2: SA units 0,2 | vmcnt(6)+barrier | read A m4,m5               | 16 MFMA
//   p3: SA units 1,3 |                    read A m6,m7               | 16 MFMA
// Ordered vmcnt retire => exactly the needed units are complete at each gate;
// stage targets are disjoint from all reads under <=1-phase wave skew.
// EPI_GU: B rows 0-127 = Wg[col..], 128-255 = Wu[col..]; silu-combine via
// LDS exchange in epilogue (block outputs 256 x 128 final cols).
template <int EPI>
__global__ __launch_bounds__(512, 2) void gemm8(
    const short* __restrict__ A, const short* __restrict__ W,
    const short* __restrict__ Wu, const float* __restrict__ bias,
    void* __restrict__ outp, int M, int N, int K)
{
  __shared__ short lds[65536];  // 128 KiB
  const int tid = threadIdx.x;
  const int wid = tid >> 6, lane = tid & 63;
  const int wr = wid >> 2, wc = wid & 3;
  const int nwg = gridDim.x * gridDim.y;
  const int orig = blockIdx.y * gridDim.x + blockIdx.x;
  const int wg = xcd_swizzle(orig, nwg);
  const int bx = wg % gridDim.x, by = wg / gridDim.x;
  const int row0 = by * 256;

  f32x4 acc[8][4];
#pragma unroll
  for (int m = 0; m < 8; ++m)
#pragma unroll
    for (int n = 0; n < 4; ++n) acc[m][n] = f32x4{0.f, 0.f, 0.f, 0.f};

  // staging geometry: unit = 64 rows x 64 k (8 KB); 1 load/thread/unit
  const int srow = tid >> 3;                // row within unit
  const int k8s = (tid & 7) ^ (srow & 7);   // inverse-swizzled source k-group
  const short* aub[4];
  const short* bub[4];
#pragma unroll
  for (int u = 0; u < 4; ++u)
    aub[u] = A + (size_t)(row0 + u * 64 + srow) * K + k8s * 8;
  if (EPI == EPI_GU) {
    const int colg = bx * 128;
#pragma unroll
    for (int u = 0; u < 2; ++u) {
      bub[u]     = W  + (size_t)(colg + u * 64 + srow) * K + k8s * 8;
      bub[u + 2] = Wu + (size_t)(colg + u * 64 + srow) * K + k8s * 8;
    }
  } else {
    const int c0 = bx * 256;
#pragma unroll
    for (int u = 0; u < 4; ++u)
      bub[u] = W + (size_t)(c0 + u * 64 + srow) * K + k8s * 8;
  }
  const int ldw = wid * 512;  // per-wave LDS slice within a unit

#define SA(d, u, kt) gload_lds16(aub[u] + (kt), &lds[(d)*16384 + (u)*4096 + ldw])
#define SB(d, u, kt) gload_lds16(bub[u] + (kt), &lds[32768 + (d)*16384 + (u)*4096 + ldw])
#define GATE(VN)                                              \
  asm volatile("s_waitcnt vmcnt(" #VN ")" ::: "memory");      \
  __builtin_amdgcn_s_barrier();

  // ds_read fragment addressing
  const int kg0 = (lane >> 4) ^ (lane & 7);
  const int kg1 = (4 + (lane >> 4)) ^ (lane & 7);
  const int aoff = (wr * 128 + (lane & 15)) * 64;
  const int boff = 32768 + (wc * 64 + (lane & 15)) * 64;

#define READ_B(d)                                                              \
  _Pragma("unroll") for (int n = 0; n < 4; ++n) {                              \
    bfr[0][n] = *(const s16x8*)&lds[(d)*16384 + boff + n * 1024 + kg0 * 8];    \
    bfr[1][n] = *(const s16x8*)&lds[(d)*16384 + boff + n * 1024 + kg1 * 8];    \
  }
#define DO_PHASE(d, p)                                                         \
  do {                                                                         \
    s16x8 a00 = *(const s16x8*)&lds[(d)*16384 + aoff + (2*(p))*1024 + kg0*8];  \
    s16x8 a01 = *(const s16x8*)&lds[(d)*16384 + aoff + (2*(p))*1024 + kg1*8];  \
    s16x8 a10 = *(const s16x8*)&lds[(d)*16384 + aoff + (2*(p)+1)*1024 + kg0*8];\
    s16x8 a11 = *(const s16x8*)&lds[(d)*16384 + aoff + (2*(p)+1)*1024 + kg1*8];\
    __builtin_amdgcn_s_setprio(1);                                             \
    _Pragma("unroll") for (int n = 0; n < 4; ++n)                              \
      acc[2*(p)][n] = __builtin_amdgcn_mfma_f32_16x16x32_bf16(a00, bfr[0][n], acc[2*(p)][n], 0, 0, 0); \
    _Pragma("unroll") for (int n = 0; n < 4; ++n)                              \
      acc[2*(p)+1][n] = __builtin_amdgcn_mfma_f32_16x16x32_bf16(a10, bfr[0][n], acc[2*(p)+1][n], 0, 0, 0); \
    _Pragma("unroll") for (int n = 0; n < 4; ++n)                              \
      acc[2*(p)][n] = __builtin_amdgcn_mfma_f32_16x16x32_bf16(a01, bfr[1][n], acc[2*(p)][n], 0, 0, 0); \
    _Pragma("unroll") for (int n = 0; n < 4; ++n)                              \
      acc[2*(p)+1][n] = __builtin_amdgcn_mfma_f32_16x16x32_bf16(a11, bfr[1][n], acc[2*(p)+1][n], 0, 0, 0); \
    __builtin_amdgcn_s_setprio(0);                                             \
  } while (0)

  // prologue: stage tile 0, buf 0, order B0,B1,B2,B3,A0,A2,A1,A3
  SB(0, 0, 0); SB(0, 1, 0); SB(0, 2, 0); SB(0, 3, 0);
  SA(0, 0, 0); SA(0, 2, 0); SA(0, 1, 0); SA(0, 3, 0);

  const int NT = K >> 6;
  for (int t = 0; t < NT - 1; ++t) {
    const int d = t & 1, d1 = d ^ 1;
    const int kn = (t + 1) * 64;
    s16x8 bfr[2][4];
    SB(d1, 0, kn); SB(d1, 1, kn);
    GATE(4);
    READ_B(d);
    DO_PHASE(d, 0);
    SB(d1, 2, kn); SB(d1, 3, kn);
    DO_PHASE(d, 1);
    SA(d1, 0, kn); SA(d1, 2, kn);
    GATE(6);
    DO_PHASE(d, 2);
    SA(d1, 1, kn); SA(d1, 3, kn);
    DO_PHASE(d, 3);
  }
  {  // final tile: no stages; tighter gates
    const int d = (NT - 1) & 1;
    s16x8 bfr[2][4];
    GATE(2);
    READ_B(d);
    DO_PHASE(d, 0);
    DO_PHASE(d, 1);
    GATE(0);
    DO_PHASE(d, 2);
    DO_PHASE(d, 3);
  }
#undef SA
#undef SB
#undef GATE
#undef READ_B
#undef DO_PHASE

  const int li = lane >> 4, lc = lane & 15;
  if (EPI == EPI_GU) {
    // silu(gate)*up combine via LDS: up waves (wc>=2) export, gate waves read
    float* fbuf = (float*)lds;
    __syncthreads();
    if (wc >= 2) {
      const int off = (wr * 2 + (wc - 2)) * 8192;
#pragma unroll
      for (int m = 0; m < 8; ++m)
#pragma unroll
        for (int i = 0; i < 4; ++i)
#pragma unroll
          for (int n = 0; n < 4; ++n)
            fbuf[off + (m * 16 + li * 4 + i) * 64 + n * 16 + lc] = acc[m][n][i];
    }
    __syncthreads();
    if (wc < 2) {
      const int off = (wr * 2 + wc) * 8192;
      const int colg = bx * 128;
#pragma unroll
      for (int m = 0; m < 8; ++m) {
#pragma unroll
        for (int i = 0; i < 4; ++i) {
          int gr = row0 + wr * 128 + m * 16 + li * 4 + i;
          if (gr < M) {
#pragma unroll
            for (int n = 0; n < 4; ++n) {
              float u = fbuf[off + (m * 16 + li * 4 + i) * 64 + n * 16 + lc];
              float g = acc[m][n][i];
              ((short*)outp)[(size_t)gr * N + colg + wc * 64 + n * 16 + lc] =
                  f2bf(silu_f(g) * u);
            }
          }
        }
      }
    }
  } else {
    const int c0 = bx * 256;
#pragma unroll
    for (int m = 0; m < 8; ++m) {
#pragma unroll
      for (int i = 0; i < 4; ++i) {
        int gr = row0 + wr * 128 + m * 16 + li * 4 + i;
        if (gr >= M) continue;
        size_t orow;
        if (EPI == EPI_SCATTER) {
          int b = gr / 900, rem = gr % 900;
          int w = rem / 9, n_ = rem % 9;
          int wi = w / 10, wj = w % 10;
          int ii = n_ / 3, jj = n_ % 3;
          int gy = wi * 3 + ii + 1; if (gy >= 30) gy -= 30;
          int gx = wj * 3 + jj + 1; if (gx >= 30) gx -= 30;
          orow = (size_t)b * 900 + gy * 30 + gx;
        } else {
          orow = (size_t)gr;
        }
#pragma unroll
        for (int n = 0; n < 4; ++n) {
          int gc = c0 + wc * 64 + n * 16 + lc;
          float v = acc[m][n][i];
          if (EPI == EPI_BIAS_BF16 || EPI == EPI_SCATTER) v += bias[gc];
          if (EPI == EPI_ADDOUT) {
            float* po = (float*)outp;
            size_t oi = orow * (size_t)N + gc;
            po[oi] = po[oi] + v;  // each output element owned by one block
          } else {
            ((short*)outp)[orow * (size_t)N + gc] = f2bf(v);
          }
        }
      }
    }
  }
}

// ================= 2-phase 128x128 GEMM (kept for small prefix GEMMs) =====
template <int EPI>
__global__ __launch_bounds__(256) void gemm2(
    const short* __restrict__ A, const short* __restrict__ W,
    const short* __restrict__ Wu, const float* __restrict__ bias,
    void* __restrict__ outp, int M, int N, int K)
{
  __shared__ short As0[8192], Bs0[8192];
  __shared__ short As1[8192], Bs1[8192];
  const int tid = threadIdx.x;
  const int wave = tid >> 6, lane = tid & 63;
  const int nwg = gridDim.x * gridDim.y;
  const int orig = blockIdx.y * gridDim.x + blockIdx.x;
  const int wg = xcd_swizzle(orig, nwg);
  const int bx = wg % gridDim.x, by = wg / gridDim.x;
  const int row0 = by * 128;
  const int col0 = (EPI == EPI_GU) ? bx * 64 : bx * 128;
  const int wr = wave >> 1, wc = wave & 1;

  f32x4 acc[4][4];
#pragma unroll
  for (int m = 0; m < 4; ++m)
#pragma unroll
    for (int n = 0; n < 4; ++n) acc[m][n] = f32x4{0.f, 0.f, 0.f, 0.f};

  const short* aptr[4];
  const short* bptr[4];
  int ldst[4];
#pragma unroll
  for (int i = 0; i < 4; ++i) {
    int e = i * 2048 + tid * 8;
    int srow = e >> 6;
    int skg = ((e >> 3) & 7) ^ (srow & 7);
    aptr[i] = A + (size_t)(row0 + srow) * K + skg * 8;
    if (EPI == EPI_GU)
      bptr[i] = (srow < 64 ? W + (size_t)(col0 + srow) * K
                           : Wu + (size_t)(col0 + srow - 64) * K) + skg * 8;
    else
      bptr[i] = W + (size_t)(col0 + srow) * K + skg * 8;
    ldst[i] = i * 2048 + wave * 512;
  }

#define STAGE(AS, BS, KT)                                   \
  do {                                                      \
    _Pragma("unroll") for (int i = 0; i < 4; ++i)           \
        gload_lds16(aptr[i] + (KT), &AS[ldst[i]]);          \
    _Pragma("unroll") for (int i = 0; i < 4; ++i)           \
        gload_lds16(bptr[i] + (KT), &BS[ldst[i]]);          \
  } while (0)

#define COMPUTE(AS, BS)                                                        \
  do {                                                                         \
    _Pragma("unroll") for (int ks = 0; ks < 2; ++ks) {                         \
      s16x8 af[4], bfr[4];                                                     \
      _Pragma("unroll") for (int m = 0; m < 4; ++m) {                          \
        int row = wr * 64 + m * 16 + (lane & 15);                              \
        int kg = (ks * 4 + (lane >> 4)) ^ (row & 7);                           \
        af[m] = *(const s16x8*)&AS[row * 64 + kg * 8];                         \
      }                                                                        \
      _Pragma("unroll") for (int n = 0; n < 4; ++n) {                          \
        int brow = (EPI == EPI_GU)                                             \
                       ? ((n < 2 ? wc * 32 + n * 16                            \
                                 : 64 + wc * 32 + (n - 2) * 16) + (lane & 15)) \
                       : (wc * 64 + n * 16 + (lane & 15));                     \
        int kg = (ks * 4 + (lane >> 4)) ^ (brow & 7);                          \
        bfr[n] = *(const s16x8*)&BS[brow * 64 + kg * 8];                       \
      }                                                                        \
      _Pragma("unroll") for (int m = 0; m < 4; ++m)                            \
          _Pragma("unroll") for (int n = 0; n < 4; ++n)                        \
              acc[m][n] = __builtin_amdgcn_mfma_f32_16x16x32_bf16(             \
                  af[m], bfr[n], acc[m][n], 0, 0, 0);                          \
    }                                                                          \
  } while (0)

  STAGE(As0, Bs0, 0);
  sync_phase();
  for (int kt = 0; kt < K; kt += 128) {
    STAGE(As1, Bs1, kt + 64);
    COMPUTE(As0, Bs0);
    sync_phase();
    if (kt + 128 < K) STAGE(As0, Bs0, kt + 128);
    COMPUTE(As1, Bs1);
    if (kt + 128 < K) sync_phase();
  }
#undef STAGE
#undef COMPUTE

  const int lr = (lane >> 4) * 4, lc = lane & 15;
#pragma unroll
  for (int m = 0; m < 4; ++m) {
#pragma unroll
    for (int i = 0; i < 4; ++i) {
      int gr = row0 + wr * 64 + m * 16 + lr + i;
      if (EPI == EPI_GU) {
#pragma unroll
        for (int n = 0; n < 2; ++n) {
          int gc = col0 + wc * 32 + n * 16 + lc;
          float v = silu_f(acc[m][n][i]) * acc[m][n + 2][i];
          ((short*)outp)[(size_t)gr * N + gc] = f2bf(v);
        }
      } else {
#pragma unroll
        for (int n = 0; n < 4; ++n) {
          int gc = col0 + wc * 64 + n * 16 + lc;
          float v = acc[m][n][i];
          ((short*)outp)[(size_t)gr * N + gc] = f2bf(v);
        }
      }
    }
  }
}

// ---------------- weight / activation conversion ----------------
__global__ __launch_bounds__(256) void cvt4_kernel(const float* __restrict__ src,
                                                   short* __restrict__ dst, int n4) {
  int i = blockIdx.x * 256 + threadIdx.x;
  if (i >= n4) return;
  f32x4 v = *(const f32x4*)(src + (size_t)i * 4);
  s16x4 o;
#pragma unroll
  for (int e = 0; e < 4; ++e) o[e] = f2bf(v[e]);
  *(s16x4*)(dst + (size_t)i * 4) = o;
}

__global__ __launch_bounds__(256) void prefix_cvt_kernel(const float* __restrict__ hs,
                                                         short* __restrict__ dst) {
  int i = blockIdx.x * 256 + threadIdx.x;
  if (i >= 512 * 128) return;
  int r = i >> 7, c4 = i & 127;
  int b = r >> 4, t = r & 15;
  f32x4 v = *(const f32x4*)(hs + ((size_t)b * 916 + t) * 512 + c4 * 4);
  s16x4 o;
#pragma unroll
  for (int e = 0; e < 4; ++e) o[e] = f2bf(v[e]);
  *(s16x4*)(dst + (size_t)r * 512 + c4 * 4) = o;
}

__global__ __launch_bounds__(512) void mean_kernel(const float* __restrict__ hs,
                                                   float* __restrict__ m) {
  int b = blockIdx.x, d = threadIdx.x;
  float s = 0.f;
#pragma unroll
  for (int t = 0; t < 16; ++t) s += hs[((size_t)b * 916 + t) * 512 + d];
  m[b * 512 + d] = s * (1.f / 16.f);
}

// grid = hs[:,16:] + mean; store bf16 residual (b,gy,gx) + bf16 windowed xw
__global__ __launch_bounds__(256) void prep_kernel(const float* __restrict__ hs,
                                                   const float* __restrict__ m,
                                                   short* __restrict__ gridb,
                                                   short* __restrict__ xw) {
  int idx = blockIdx.x * 256 + threadIdx.x;
  if (idx >= 32 * 900 * 128) return;
  int c4 = idx & 127;
  int row = idx >> 7;
  int b = row / 900, rem = row % 900;
  int gy = rem / 30, gx = rem % 30;
  f32x4 v = *(const f32x4*)(hs + ((size_t)b * 916 + 16 + rem) * 512 + c4 * 4);
  f32x4 mm = *(const f32x4*)(m + b * 512 + c4 * 4);
  v += mm;
  s16x4 o;
#pragma unroll
  for (int e = 0; e < 4; ++e) o[e] = f2bf(v[e]);
  *(s16x4*)(gridb + (size_t)row * 512 + c4 * 4) = o;
  int ry = gy + 29; if (ry >= 30) ry -= 30;
  int rx = gx + 29; if (rx >= 30) rx -= 30;
  int wi = ry / 3, ii = ry % 3, wj = rx / 3, jj = rx % 3;
  size_t xrow = (size_t)((b * 100 + wi * 10 + wj) * 9 + ii * 3 + jj);
  *(s16x4*)(xw + xrow * 512 + c4 * 4) = o;
}

// ---------------- windowed attention (9 tokens, 8 heads per window) ----------
__global__ __launch_bounds__(256) void attn_kernel(const short* __restrict__ qkv,
                                                   const float* __restrict__ rel_bias,
                                                   short* __restrict__ outp) {
  __shared__ short sq[9 * 512];
  __shared__ short sk[9 * 512];
  __shared__ short sv[9 * 512];
  __shared__ float sS[648];
  const int wlin = blockIdx.x;
  const int w = wlin % 100;
  const int wi = w / 10, wj = w % 10;
  const int tid = threadIdx.x;
  const short* base = qkv + (size_t)wlin * 9 * 1536;
  for (int idx = tid; idx < 1728; idx += 256) {
    int n = idx / 192, c8 = idx % 192;
    s16x8 v = *(const s16x8*)(base + (size_t)n * 1536 + c8 * 8);
    int which = c8 >> 6;
    short* dst = (which == 0) ? sq : (which == 1) ? sk : sv;
    *(s16x8*)(dst + n * 512 + (c8 & 63) * 8) = v;
  }
  __syncthreads();
  for (int idx = tid; idx < 648; idx += 256) {
    int h = idx / 81, r = idx % 81, i = r / 9, j = r % 9;
    const short* qp = sq + i * 512 + h * 64;
    const short* kp = sk + j * 512 + h * 64;
    float dot = 0.f;
#pragma unroll
    for (int c = 0; c < 8; ++c) {
      s16x8 qv = *(const s16x8*)(qp + c * 8);
      s16x8 kv = *(const s16x8*)(kp + c * 8);
#pragma unroll
      for (int e = 0; e < 8; ++e) dot += bf2f(qv[e]) * bf2f(kv[e]);
    }
    float s = dot * 0.125f;
    int ia = i / 3, ja = i % 3, ib = j / 3, jb = j % 3;
    s += rel_bias[(5 * (ia - ib + 2) + (ja - jb + 2)) * 8 + h];
    int ra = wi * 3 + ia, ca = wj * 3 + ja, rb = wi * 3 + ib, cb = wj * 3 + jb;
    int rga = (ra < 27) ? 0 : (ra < 29) ? 1 : 2;
    int cga = (ca < 27) ? 0 : (ca < 29) ? 1 : 2;
    int rgb = (rb < 27) ? 0 : (rb < 29) ? 1 : 2;
    int cgb = (cb < 27) ? 0 : (cb < 29) ? 1 : 2;
    if (rga * 3 + cga != rgb * 3 + cgb) s -= 100.f;
    sS[idx] = s;
  }
  __syncthreads();
  if (tid < 72) {
    float* row = sS + tid * 9;
    float mx = row[0];
#pragma unroll
    for (int j = 1; j < 9; ++j) mx = fmaxf(mx, row[j]);
    float e[9], sum = 0.f;
#pragma unroll
    for (int j = 0; j < 9; ++j) { e[j] = __expf(row[j] - mx); sum += e[j]; }
    float inv = 1.f / sum;
#pragma unroll
    for (int j = 0; j < 9; ++j) row[j] = e[j] * inv;
  }
  __syncthreads();
  for (int idx = tid; idx < 576; idx += 256) {
    int h = idx / 72, r = idx % 72, i = r / 8, d8 = r % 8;
    const float* p = sS + (h * 9 + i) * 9;
    float a[8] = {0, 0, 0, 0, 0, 0, 0, 0};
#pragma unroll
    for (int j = 0; j < 9; ++j) {
      float pj = p[j];
      s16x8 vv = *(const s16x8*)(sv + j * 512 + h * 64 + d8 * 8);
#pragma unroll
      for (int e = 0; e < 8; ++e) a[e] += pj * bf2f(vv[e]);
    }
    s16x8 o;
#pragma unroll
    for (int e = 0; e < 8; ++e) o[e] = f2bf(a[e]);
    *(s16x8*)(outp + ((size_t)wlin * 9 + i) * 512 + h * 64 + d8 * 8) = o;
  }
}

// ---------------- add + RMS norm variants (one wave per row of 512) ---------
__global__ __launch_bounds__(64) void addnorm1_kernel(const short* __restrict__ g,
                                                      const short* __restrict__ p,
                                                      float* __restrict__ out,
                                                      short* __restrict__ hsb) {
  int row = blockIdx.x, lane = threadIdx.x;
  size_t off = (size_t)row * 512 + lane * 8;
  s16x8 a8 = *(const s16x8*)(g + off);
  s16x8 b8 = *(const s16x8*)(p + off);
  float x[8];
  float ss = 0.f;
#pragma unroll
  for (int e = 0; e < 8; ++e) {
    x[e] = bf2f(a8[e]) + bf2f(b8[e]);
    ss += x[e] * x[e];
  }
  ss = wave_allsum(ss);
  float sc = rsqrtf(ss * (1.f / 512.f) + 1e-5f);
  int b_ = row / 900, t = row % 900;
  size_t orow = ((size_t)b_ * 916 + 16 + t) * 512 + lane * 8;
  s16x8 o;
#pragma unroll
  for (int e = 0; e < 8; ++e) {
    x[e] *= sc;
    o[e] = f2bf(x[e]);
  }
  *(f32x4*)(out + orow) = f32x4{x[0], x[1], x[2], x[3]};
  *(f32x4*)(out + orow + 4) = f32x4{x[4], x[5], x[6], x[7]};
  *(s16x8*)(hsb + orow) = o;
}

__global__ __launch_bounds__(64) void prefix_addnorm_kernel(const float* __restrict__ hs,
                                                            const short* __restrict__ pd,
                                                            float* __restrict__ out,
                                                            short* __restrict__ hsb) {
  int r = blockIdx.x, lane = threadIdx.x;
  int b = r >> 4, t = r & 15;
  size_t orow = ((size_t)b * 916 + t) * 512;
  f32x4 x[2];
  float ss = 0.f;
#pragma unroll
  for (int i = 0; i < 2; ++i) {
    f32x4 a = *(const f32x4*)(hs + orow + i * 256 + lane * 4);
    s16x4 d = *(const s16x4*)(pd + (size_t)r * 512 + i * 256 + lane * 4);
#pragma unroll
    for (int e = 0; e < 4; ++e) a[e] += bf2f(d[e]);
    x[i] = a;
    ss += a[0] * a[0] + a[1] * a[1] + a[2] * a[2] + a[3] * a[3];
  }
  ss = wave_allsum(ss);
  float sc = rsqrtf(ss * (1.f / 512.f) + 1e-5f);
#pragma unroll
  for (int i = 0; i < 2; ++i) {
    f32x4 y = x[i] * sc;
    *(f32x4*)(out + orow + i * 256 + lane * 4) = y;
    s16x4 o;
#pragma unroll
    for (int e = 0; e < 4; ++e) o[e] = f2bf(y[e]);
    *(s16x4*)(hsb + orow + i * 256 + lane * 4) = o;
  }
}

__global__ __launch_bounds__(64) void final_addnorm_kernel(float* __restrict__ io) {
  int row = blockIdx.x, lane = threadIdx.x;
  size_t off = (size_t)row * 512;
  f32x4 x[2];
  float ss = 0.f;
#pragma unroll
  for (int i = 0; i < 2; ++i) {
    f32x4 a = *(const f32x4*)(io + off + i * 256 + lane * 4);
    x[i] = a;
    ss += a[0] * a[0] + a[1] * a[1] + a[2] * a[2] + a[3] * a[3];
  }
  ss = wave_allsum(ss);
  float sc = rsqrtf(ss * (1.f / 512.f) + 1e-5f);
#pragma unroll
  for (int i = 0; i < 2; ++i)
    *(f32x4*)(io + off + i * 256 + lane * 4) = x[i] * sc;
}

// ---------------- workspace layout (bytes; liveness-overlaid) ----------------
// Peak 194.5 MB < 223.7 MB proven budget. Pad rows cover 256-row tile staging.
static constexpr size_t OFF_WQKV   = 0;
static constexpr size_t OFF_WPROJ  = 1572864;
static constexpr size_t OFF_WGU    = 2097152;
static constexpr size_t OFF_WDOWN  = 5242880;
static constexpr size_t OFF_WPGU   = 6815744;
static constexpr size_t OFF_WPDOWN = 9961472;
static constexpr size_t OFF_MEAN   = 11534336;
static constexpr size_t OFF_PREFB  = 11599872;
static constexpr size_t OFF_PINTER = 13697024;
static constexpr size_t OFF_PDOUT  = 15269888;                // end 15794176
static constexpr size_t OFF_GRIDB  = 16777216;                // 28800*512*2 -> 46268416
static constexpr size_t OFF_XW     = 46268416;                // 28928*512*2 -> 75890688 (pad)
static constexpr size_t OFF_QKV    = 75890688;                // 28800*1536*2 -> 164364288
static constexpr size_t OFF_ATTNO  = OFF_XW;                  // reuse (xw dead)
static constexpr size_t OFF_PROJS  = OFF_QKV;                 // reuse (qkvb dead)
static constexpr size_t OFF_INTER  = OFF_GRIDB;               // 29440*1536*2 -> 107216896 (all dead)
static constexpr size_t OFF_HSB    = 164364288;               // 29440*512*2 -> 194510848 (pad)

extern "C" void kernel_launch(void* const* d_in, const int* in_sizes, int n_in,
                              void* d_out, int out_size, void* d_ws, size_t ws_size,
                              hipStream_t stream) {
  const float* hs      = (const float*)d_in[0];
  const float* qkv_w   = (const float*)d_in[1];
  const float* qkv_b   = (const float*)d_in[2];
  const float* proj_w  = (const float*)d_in[3];
  const float* proj_b  = (const float*)d_in[4];
  const float* rel_b   = (const float*)d_in[5];
  const float* gu_w    = (const float*)d_in[6];
  const float* down_w  = (const float*)d_in[7];
  const float* pgu_w   = (const float*)d_in[8];
  const float* pdown_w = (const float*)d_in[9];

  char* ws = (char*)d_ws;
  short* Wqkv   = (short*)(ws + OFF_WQKV);
  short* Wproj  = (short*)(ws + OFF_WPROJ);
  short* Wgu    = (short*)(ws + OFF_WGU);
  short* Wdown  = (short*)(ws + OFF_WDOWN);
  short* Wpgu   = (short*)(ws + OFF_WPGU);
  short* Wpdown = (short*)(ws + OFF_WPDOWN);
  float* meanb  = (float*)(ws + OFF_MEAN);
  short* prefb  = (short*)(ws + OFF_PREFB);
  short* pinter = (short*)(ws + OFF_PINTER);
  short* pdout  = (short*)(ws + OFF_PDOUT);
  short* gridb  = (short*)(ws + OFF_GRIDB);
  short* xw     = (short*)(ws + OFF_XW);
  short* qkvb   = (short*)(ws + OFF_QKV);
  short* attno  = (short*)(ws + OFF_ATTNO);
  short* projs  = (short*)(ws + OFF_PROJS);
  short* interb = (short*)(ws + OFF_INTER);
  short* hsb    = (short*)(ws + OFF_HSB);
  float* outf   = (float*)d_out;

  // 1. weight fp32 -> bf16
  cvt4_kernel<<<768, 256, 0, stream>>>(qkv_w, Wqkv, 786432 / 4);
  cvt4_kernel<<<256, 256, 0, stream>>>(proj_w, Wproj, 262144 / 4);
  cvt4_kernel<<<1536, 256, 0, stream>>>(gu_w, Wgu, 1572864 / 4);
  cvt4_kernel<<<768, 256, 0, stream>>>(down_w, Wdown, 786432 / 4);
  cvt4_kernel<<<1536, 256, 0, stream>>>(pgu_w, Wpgu, 1572864 / 4);
  cvt4_kernel<<<768, 256, 0, stream>>>(pdown_w, Wpdown, 786432 / 4);
  prefix_cvt_kernel<<<256, 256, 0, stream>>>(hs, prefb);

  // 2. prefix mean -> bf16 residual + windowed bf16 input
  mean_kernel<<<32, 512, 0, stream>>>(hs, meanb);
  prep_kernel<<<14400, 256, 0, stream>>>(hs, meanb, gridb, xw);

  // 3. QKV projection (M=28800 pad 113 tiles, N=1536, K=512)
  gemm8<EPI_BIAS_BF16><<<dim3(6, 113), 512, 0, stream>>>(
      xw, Wqkv, nullptr, qkv_b, qkvb, 28800, 1536, 512);
  // 4. windowed attention
  attn_kernel<<<3200, 256, 0, stream>>>(qkvb, rel_b, attno);

  // 5. output projection + scatter (N=512)
  gemm8<EPI_SCATTER><<<dim3(2, 113), 512, 0, stream>>>(
      attno, Wproj, nullptr, proj_b, projs, 28800, 512, 512);
  // 6. x = rms(residual + proj) -> fp32 d_out + bf16 hsb
  addnorm1_kernel<<<28800, 64, 0, stream>>>(gridb, projs, outf, hsb);

  // 7. prefix branch (small): 2-phase gemms + rms
  gemm2<EPI_GU><<<dim3(24, 4), 256, 0, stream>>>(
      prefb, Wpgu, Wpgu + 1536 * 512, nullptr, pinter, 512, 1536, 512);
  gemm2<EPI_BF16><<<dim3(4, 4), 256, 0, stream>>>(
      pinter, Wpdown, nullptr, nullptr, pdout, 512, 512, 1536);
  prefix_addnorm_kernel<<<512, 64, 0, stream>>>(hs, pdout, outf, hsb);

  // 8. full-sequence fused swiglu (M=29312 pad 115 tiles); down adds into d_out
  gemm8<EPI_GU><<<dim3(12, 115), 512, 0, stream>>>(
      hsb, Wgu, Wgu + 1536 * 512, nullptr, interb, 29312, 1536, 512);
  gemm8<EPI_ADDOUT><<<dim3(2, 115), 512, 0, stream>>>(
      interb, Wdown, nullptr, nullptr, outf, 29312, 512, 1536);
  // 9. out = rms(out) in place
  final_addnorm_kernel<<<29312, 64, 0, stream>>>(outf);

  (void)in_sizes; (void)n_in; (void)out_size; (void)ws_size;
}

// Round 6
// 441.259 us; speedup vs baseline: 1.3024x; 1.1107x over previous
//
#include <hip/hip_runtime.h>
#include <cstdint>
#include <cstddef>

typedef float f32x4 __attribute__((ext_vector_type(4)));
typedef short s16x8 __attribute__((ext_vector_type(8)));
typedef short s16x4 __attribute__((ext_vector_type(4)));

#define DEV static __device__ __forceinline__

DEV float bf2f(short s) {
  union { unsigned u; float f; } c;
  c.u = ((unsigned)(unsigned short)s) << 16;
  return c.f;
}
DEV short f2bf(float f) {
  union { float f; unsigned u; } c;
  c.f = f;
  unsigned r = c.u + 0x7fffu + ((c.u >> 16) & 1u);
  return (short)(r >> 16);
}
DEV float wave_allsum(float v) {
#pragma unroll
  for (int off = 32; off > 0; off >>= 1) v += __shfl_xor(v, off, 64);
  return v;
}
DEV void gload_lds16(const void* g, void* l) {
  __builtin_amdgcn_global_load_lds(
      (const __attribute__((address_space(1))) void*)g,
      (__attribute__((address_space(3))) void*)l, 16, 0, 0);
}
DEV float silu_f(float g) { return g / (1.f + __expf(-g)); }

// bijective XCD-chunk swizzle (m204)
DEV int xcd_swizzle(int orig, int nwg) {
  int q = nwg >> 3, r = nwg & 7;
  int xcd = orig & 7, pos = orig >> 3;
  return (xcd < r ? xcd * (q + 1) : r * (q + 1) + (xcd - r) * q) + pos;
}

DEV void sync_phase() {
  asm volatile("s_waitcnt vmcnt(0)" ::: "memory");
  __builtin_amdgcn_s_barrier();
  __builtin_amdgcn_sched_barrier(0);
}

enum { EPI_BF16 = 0, EPI_BIAS_BF16 = 1, EPI_SCATTER = 4, EPI_ADDOUT = 5, EPI_GU = 6 };

// ================= 8-phase 256x256 bf16 GEMM (QKV / proj / down) =========
template <int EPI>
__global__ __launch_bounds__(512, 2) void gemm8(
    const short* __restrict__ A, const short* __restrict__ W,
    const float* __restrict__ bias, void* __restrict__ outp,
    int M, int N, int K)
{
  __shared__ short lds[65536];  // 128 KiB
  const int tid = threadIdx.x;
  const int wid = tid >> 6, lane = tid & 63;
  const int wr = wid >> 2, wc = wid & 3;
  const int nwg = gridDim.x * gridDim.y;
  const int orig = blockIdx.y * gridDim.x + blockIdx.x;
  const int wg = xcd_swizzle(orig, nwg);
  const int bx = wg % gridDim.x, by = wg / gridDim.x;
  const int row0 = by * 256;
  const int c0 = bx * 256;

  f32x4 acc[8][4];
#pragma unroll
  for (int m = 0; m < 8; ++m)
#pragma unroll
    for (int n = 0; n < 4; ++n) acc[m][n] = f32x4{0.f, 0.f, 0.f, 0.f};

  const int srow = tid >> 3;
  const int k8s = (tid & 7) ^ (srow & 7);
  const short* aub[4];
  const short* bub[4];
#pragma unroll
  for (int u = 0; u < 4; ++u) {
    aub[u] = A + (size_t)(row0 + u * 64 + srow) * K + k8s * 8;
    bub[u] = W + (size_t)(c0 + u * 64 + srow) * K + k8s * 8;
  }
  const int ldw = wid * 512;

#define SA(d, u, kt) gload_lds16(aub[u] + (kt), &lds[(d)*16384 + (u)*4096 + ldw])
#define SB(d, u, kt) gload_lds16(bub[u] + (kt), &lds[32768 + (d)*16384 + (u)*4096 + ldw])
#define GATE(VN)                                              \
  asm volatile("s_waitcnt vmcnt(" #VN ")" ::: "memory");      \
  __builtin_amdgcn_s_barrier();                               \
  __builtin_amdgcn_sched_barrier(0);

  const int kg0 = (lane >> 4) ^ (lane & 7);
  const int kg1 = (4 + (lane >> 4)) ^ (lane & 7);
  const int aoff = (wr * 128 + (lane & 15)) * 64;
  const int boff = 32768 + (wc * 64 + (lane & 15)) * 64;

#define READ_B(d)                                                              \
  _Pragma("unroll") for (int n = 0; n < 4; ++n) {                              \
    bfr[0][n] = *(const s16x8*)&lds[(d)*16384 + boff + n * 1024 + kg0 * 8];    \
    bfr[1][n] = *(const s16x8*)&lds[(d)*16384 + boff + n * 1024 + kg1 * 8];    \
  }
#define DO_PHASE(d, p)                                                         \
  do {                                                                         \
    s16x8 a00 = *(const s16x8*)&lds[(d)*16384 + aoff + (2*(p))*1024 + kg0*8];  \
    s16x8 a01 = *(const s16x8*)&lds[(d)*16384 + aoff + (2*(p))*1024 + kg1*8];  \
    s16x8 a10 = *(const s16x8*)&lds[(d)*16384 + aoff + (2*(p)+1)*1024 + kg0*8];\
    s16x8 a11 = *(const s16x8*)&lds[(d)*16384 + aoff + (2*(p)+1)*1024 + kg1*8];\
    __builtin_amdgcn_s_setprio(1);                                             \
    _Pragma("unroll") for (int n = 0; n < 4; ++n)                              \
      acc[2*(p)][n] = __builtin_amdgcn_mfma_f32_16x16x32_bf16(a00, bfr[0][n], acc[2*(p)][n], 0, 0, 0); \
    _Pragma("unroll") for (int n = 0; n < 4; ++n)                              \
      acc[2*(p)+1][n] = __builtin_amdgcn_mfma_f32_16x16x32_bf16(a10, bfr[0][n], acc[2*(p)+1][n], 0, 0, 0); \
    _Pragma("unroll") for (int n = 0; n < 4; ++n)                              \
      acc[2*(p)][n] = __builtin_amdgcn_mfma_f32_16x16x32_bf16(a01, bfr[1][n], acc[2*(p)][n], 0, 0, 0); \
    _Pragma("unroll") for (int n = 0; n < 4; ++n)                              \
      acc[2*(p)+1][n] = __builtin_amdgcn_mfma_f32_16x16x32_bf16(a11, bfr[1][n], acc[2*(p)+1][n], 0, 0, 0); \
    __builtin_amdgcn_s_setprio(0);                                             \
  } while (0)

  SB(0, 0, 0); SB(0, 1, 0); SB(0, 2, 0); SB(0, 3, 0);
  SA(0, 0, 0); SA(0, 2, 0); SA(0, 1, 0); SA(0, 3, 0);

  const int NT = K >> 6;
  for (int t = 0; t < NT - 1; ++t) {
    const int d = t & 1, d1 = d ^ 1;
    const int kn = (t + 1) * 64;
    s16x8 bfr[2][4];
    SB(d1, 0, kn); SB(d1, 1, kn);
    GATE(4);
    READ_B(d);
    DO_PHASE(d, 0);
    SB(d1, 2, kn); SB(d1, 3, kn);
    DO_PHASE(d, 1);
    SA(d1, 0, kn); SA(d1, 2, kn);
    GATE(6);
    DO_PHASE(d, 2);
    SA(d1, 1, kn); SA(d1, 3, kn);
    DO_PHASE(d, 3);
  }
  {
    const int d = (NT - 1) & 1;
    s16x8 bfr[2][4];
    GATE(2);
    READ_B(d);
    DO_PHASE(d, 0);
    DO_PHASE(d, 1);
    GATE(0);
    DO_PHASE(d, 2);
    DO_PHASE(d, 3);
  }
#undef SA
#undef SB
#undef READ_B
#undef DO_PHASE

  const int li = lane >> 4, lc = lane & 15;
#pragma unroll
  for (int m = 0; m < 8; ++m) {
#pragma unroll
    for (int i = 0; i < 4; ++i) {
      int gr = row0 + wr * 128 + m * 16 + li * 4 + i;
      if (gr >= M) continue;
      size_t orow;
      if (EPI == EPI_SCATTER) {
        int b = gr / 900, rem = gr % 900;
        int w = rem / 9, n_ = rem % 9;
        int wi = w / 10, wj = w % 10;
        int ii = n_ / 3, jj = n_ % 3;
        int gy = wi * 3 + ii + 1; if (gy >= 30) gy -= 30;
        int gx = wj * 3 + jj + 1; if (gx >= 30) gx -= 30;
        orow = (size_t)b * 900 + gy * 30 + gx;
      } else {
        orow = (size_t)gr;
      }
#pragma unroll
      for (int n = 0; n < 4; ++n) {
        int gc = c0 + wc * 64 + n * 16 + lc;
        float v = acc[m][n][i];
        if (EPI == EPI_BIAS_BF16 || EPI == EPI_SCATTER) v += bias[gc];
        if (EPI == EPI_ADDOUT) {
          float* po = (float*)outp;
          size_t oi = orow * (size_t)N + gc;
          po[oi] = po[oi] + v;
        } else {
          ((short*)outp)[orow * (size_t)N + gc] = f2bf(v);
        }
      }
    }
  }
}

// ============ 8-phase 256-row GU GEMM, 4x2 waves, in-register combine ======
// Wave (wr 0..3, wc 0..1): rows wr*64..+63, gate cols colg+wc*64..+63 and the
// SAME up cols -> silu-combine entirely in registers (no epilogue LDS).
// Phases: p0,p1 = gate MFMA (B units 0,1) ; p2,p3 = up MFMA (B units 2,3).
// Stage order per tile: A0..A3,B0..B3; gates vmcnt(2) before p0 (leaves B2,B3
// of cur tile), vmcnt(4) before p2 (leaves A0-A3 of next tile). Traced
// race-free incl. prologue and final peel.
__global__ __launch_bounds__(512, 2) void gemm8gu(
    const short* __restrict__ A, const short* __restrict__ Wg,
    const short* __restrict__ Wu, short* __restrict__ outp, int M, int K)
{
  __shared__ short lds[65536];
  const int tid = threadIdx.x;
  const int wid = tid >> 6, lane = tid & 63;
  const int wr = wid >> 1, wc = wid & 1;
  const int nwg = gridDim.x * gridDim.y;
  const int orig = blockIdx.y * gridDim.x + blockIdx.x;
  const int wg = xcd_swizzle(orig, nwg);
  const int bx = wg % gridDim.x, by = wg / gridDim.x;
  const int row0 = by * 256;
  const int colg = bx * 128;

  f32x4 accg[4][4], accu[4][4];
#pragma unroll
  for (int m = 0; m < 4; ++m)
#pragma unroll
    for (int n = 0; n < 4; ++n) {
      accg[m][n] = f32x4{0.f, 0.f, 0.f, 0.f};
      accu[m][n] = f32x4{0.f, 0.f, 0.f, 0.f};
    }

  const int srow = tid >> 3;
  const int k8s = (tid & 7) ^ (srow & 7);
  const short* aub[4];
  const short* bub[4];
#pragma unroll
  for (int u = 0; u < 4; ++u)
    aub[u] = A + (size_t)(row0 + u * 64 + srow) * K + k8s * 8;
#pragma unroll
  for (int u = 0; u < 2; ++u) {
    bub[u]     = Wg + (size_t)(colg + u * 64 + srow) * K + k8s * 8;
    bub[u + 2] = Wu + (size_t)(colg + u * 64 + srow) * K + k8s * 8;
  }
  const int ldw = wid * 512;

#define SA(d, u, kt) gload_lds16(aub[u] + (kt), &lds[(d)*16384 + (u)*4096 + ldw])
#define SB(d, u, kt) gload_lds16(bub[u] + (kt), &lds[32768 + (d)*16384 + (u)*4096 + ldw])

  const int kg0 = (lane >> 4) ^ (lane & 7);
  const int kg1 = (4 + (lane >> 4)) ^ (lane & 7);
  const int aoff = (wr * 64 + (lane & 15)) * 64;
  const int bgoff = 32768 + (wc * 64 + (lane & 15)) * 64;
  const int buoff = 32768 + (128 + wc * 64 + (lane & 15)) * 64;

#define READ_BF(d, BOFF)                                                       \
  _Pragma("unroll") for (int n = 0; n < 4; ++n) {                              \
    bfr[0][n] = *(const s16x8*)&lds[(d)*16384 + (BOFF) + n * 1024 + kg0 * 8];  \
    bfr[1][n] = *(const s16x8*)&lds[(d)*16384 + (BOFF) + n * 1024 + kg1 * 8];  \
  }
#define PHASE2(d, p, ACC)                                                      \
  do {                                                                         \
    s16x8 a00 = *(const s16x8*)&lds[(d)*16384 + aoff + (2*(p))*1024 + kg0*8];  \
    s16x8 a01 = *(const s16x8*)&lds[(d)*16384 + aoff + (2*(p))*1024 + kg1*8];  \
    s16x8 a10 = *(const s16x8*)&lds[(d)*16384 + aoff + (2*(p)+1)*1024 + kg0*8];\
    s16x8 a11 = *(const s16x8*)&lds[(d)*16384 + aoff + (2*(p)+1)*1024 + kg1*8];\
    __builtin_amdgcn_s_setprio(1);                                             \
    _Pragma("unroll") for (int n = 0; n < 4; ++n)                              \
      ACC[2*(p)][n] = __builtin_amdgcn_mfma_f32_16x16x32_bf16(a00, bfr[0][n], ACC[2*(p)][n], 0, 0, 0); \
    _Pragma("unroll") for (int n = 0; n < 4; ++n)                              \
      ACC[2*(p)+1][n] = __builtin_amdgcn_mfma_f32_16x16x32_bf16(a10, bfr[0][n], ACC[2*(p)+1][n], 0, 0, 0); \
    _Pragma("unroll") for (int n = 0; n < 4; ++n)                              \
      ACC[2*(p)][n] = __builtin_amdgcn_mfma_f32_16x16x32_bf16(a01, bfr[1][n], ACC[2*(p)][n], 0, 0, 0); \
    _Pragma("unroll") for (int n = 0; n < 4; ++n)                              \
      ACC[2*(p)+1][n] = __builtin_amdgcn_mfma_f32_16x16x32_bf16(a11, bfr[1][n], ACC[2*(p)+1][n], 0, 0, 0); \
    __builtin_amdgcn_s_setprio(0);                                             \
  } while (0)
#define GATE(VN)                                              \
  asm volatile("s_waitcnt vmcnt(" #VN ")" ::: "memory");      \
  __builtin_amdgcn_s_barrier();                               \
  __builtin_amdgcn_sched_barrier(0);

  // prologue: tile 0 into buf 0: A0..A3, B0..B3
  SA(0, 0, 0); SA(0, 1, 0); SA(0, 2, 0); SA(0, 3, 0);
  SB(0, 0, 0); SB(0, 1, 0); SB(0, 2, 0); SB(0, 3, 0);

  const int NT = K >> 6;
  for (int t = 0; t < NT - 1; ++t) {
    const int d = t & 1, d1 = d ^ 1;
    const int kn = (t + 1) * 64;
    s16x8 bfr[2][4];
    GATE(2);                       // A0-A3,B0,B1 of tile t complete
    READ_BF(d, bgoff);
    PHASE2(d, 0, accg);
    SA(d1, 0, kn); SA(d1, 1, kn);
    PHASE2(d, 1, accg);
    SA(d1, 2, kn); SA(d1, 3, kn);
    GATE(4);                       // B2,B3 of tile t complete
    READ_BF(d, buoff);
    PHASE2(d, 0, accu);
    SB(d1, 0, kn); SB(d1, 1, kn);
    PHASE2(d, 1, accu);
    SB(d1, 2, kn); SB(d1, 3, kn);
  }
  {
    const int d = (NT - 1) & 1;
    s16x8 bfr[2][4];
    GATE(2);
    READ_BF(d, bgoff);
    PHASE2(d, 0, accg);
    PHASE2(d, 1, accg);
    GATE(0);
    READ_BF(d, buoff);
    PHASE2(d, 0, accu);
    PHASE2(d, 1, accu);
  }
#undef SA
#undef SB
#undef READ_BF
#undef PHASE2
#undef GATE

  const int li = lane >> 4, lc = lane & 15;
#pragma unroll
  for (int m = 0; m < 4; ++m) {
#pragma unroll
    for (int i = 0; i < 4; ++i) {
      int gr = row0 + wr * 64 + m * 16 + li * 4 + i;
      if (gr >= M) continue;
#pragma unroll
      for (int n = 0; n < 4; ++n) {
        int gc = colg + wc * 64 + n * 16 + lc;
        outp[(size_t)gr * 1536 + gc] = f2bf(silu_f(accg[m][n][i]) * accu[m][n][i]);
      }
    }
  }
}

// ================= 2-phase 128x128 GEMM (small prefix GEMMs) =====
template <int EPI>
__global__ __launch_bounds__(256) void gemm2(
    const short* __restrict__ A, const short* __restrict__ W,
    const short* __restrict__ Wu, const float* __restrict__ bias,
    void* __restrict__ outp, int M, int N, int K)
{
  __shared__ short As0[8192], Bs0[8192];
  __shared__ short As1[8192], Bs1[8192];
  const int tid = threadIdx.x;
  const int wave = tid >> 6, lane = tid & 63;
  const int nwg = gridDim.x * gridDim.y;
  const int orig = blockIdx.y * gridDim.x + blockIdx.x;
  const int wg = xcd_swizzle(orig, nwg);
  const int bx = wg % gridDim.x, by = wg / gridDim.x;
  const int row0 = by * 128;
  const int col0 = (EPI == EPI_GU) ? bx * 64 : bx * 128;
  const int wr = wave >> 1, wc = wave & 1;

  f32x4 acc[4][4];
#pragma unroll
  for (int m = 0; m < 4; ++m)
#pragma unroll
    for (int n = 0; n < 4; ++n) acc[m][n] = f32x4{0.f, 0.f, 0.f, 0.f};

  const short* aptr[4];
  const short* bptr[4];
  int ldst[4];
#pragma unroll
  for (int i = 0; i < 4; ++i) {
    int e = i * 2048 + tid * 8;
    int srow = e >> 6;
    int skg = ((e >> 3) & 7) ^ (srow & 7);
    aptr[i] = A + (size_t)(row0 + srow) * K + skg * 8;
    if (EPI == EPI_GU)
      bptr[i] = (srow < 64 ? W + (size_t)(col0 + srow) * K
                           : Wu + (size_t)(col0 + srow - 64) * K) + skg * 8;
    else
      bptr[i] = W + (size_t)(col0 + srow) * K + skg * 8;
    ldst[i] = i * 2048 + wave * 512;
  }

#define STAGE(AS, BS, KT)                                   \
  do {                                                      \
    _Pragma("unroll") for (int i = 0; i < 4; ++i)           \
        gload_lds16(aptr[i] + (KT), &AS[ldst[i]]);          \
    _Pragma("unroll") for (int i = 0; i < 4; ++i)           \
        gload_lds16(bptr[i] + (KT), &BS[ldst[i]]);          \
  } while (0)

#define COMPUTE(AS, BS)                                                        \
  do {                                                                         \
    _Pragma("unroll") for (int ks = 0; ks < 2; ++ks) {                         \
      s16x8 af[4], bfr[4];                                                     \
      _Pragma("unroll") for (int m = 0; m < 4; ++m) {                          \
        int row = wr * 64 + m * 16 + (lane & 15);                              \
        int kg = (ks * 4 + (lane >> 4)) ^ (row & 7);                           \
        af[m] = *(const s16x8*)&AS[row * 64 + kg * 8];                         \
      }                                                                        \
      _Pragma("unroll") for (int n = 0; n < 4; ++n) {                          \
        int brow = (EPI == EPI_GU)                                             \
                       ? ((n < 2 ? wc * 32 + n * 16                            \
                                 : 64 + wc * 32 + (n - 2) * 16) + (lane & 15)) \
                       : (wc * 64 + n * 16 + (lane & 15));                     \
        int kg = (ks * 4 + (lane >> 4)) ^ (brow & 7);                          \
        bfr[n] = *(const s16x8*)&BS[brow * 64 + kg * 8];                       \
      }                                                                        \
      _Pragma("unroll") for (int m = 0; m < 4; ++m)                            \
          _Pragma("unroll") for (int n = 0; n < 4; ++n)                        \
              acc[m][n] = __builtin_amdgcn_mfma_f32_16x16x32_bf16(             \
                  af[m], bfr[n], acc[m][n], 0, 0, 0);                          \
    }                                                                          \
  } while (0)

  STAGE(As0, Bs0, 0);
  sync_phase();
  for (int kt = 0; kt < K; kt += 128) {
    STAGE(As1, Bs1, kt + 64);
    COMPUTE(As0, Bs0);
    sync_phase();
    if (kt + 128 < K) STAGE(As0, Bs0, kt + 128);
    COMPUTE(As1, Bs1);
    if (kt + 128 < K) sync_phase();
  }
#undef STAGE
#undef COMPUTE

  const int lr = (lane >> 4) * 4, lc = lane & 15;
#pragma unroll
  for (int m = 0; m < 4; ++m) {
#pragma unroll
    for (int i = 0; i < 4; ++i) {
      int gr = row0 + wr * 64 + m * 16 + lr + i;
      if (EPI == EPI_GU) {
#pragma unroll
        for (int n = 0; n < 2; ++n) {
          int gc = col0 + wc * 32 + n * 16 + lc;
          float v = silu_f(acc[m][n][i]) * acc[m][n + 2][i];
          ((short*)outp)[(size_t)gr * N + gc] = f2bf(v);
        }
      } else {
#pragma unroll
        for (int n = 0; n < 4; ++n) {
          int gc = col0 + wc * 64 + n * 16 + lc;
          ((short*)outp)[(size_t)gr * N + gc] = f2bf(acc[m][n][i]);
        }
      }
    }
  }
}

// ---------------- fused weight conversion (dst region is contiguous) --------
// segments (float4 units): qkv 196608 | proj 65536 | gu 393216 | down 196608
//                        | pgu 393216 | pdown 196608  -> total 1441792
__global__ __launch_bounds__(256) void cvt_all_kernel(
    const float* __restrict__ s_qkv, const float* __restrict__ s_proj,
    const float* __restrict__ s_gu, const float* __restrict__ s_down,
    const float* __restrict__ s_pgu, const float* __restrict__ s_pdown,
    short* __restrict__ dst) {
  int i = blockIdx.x * 256 + threadIdx.x;
  if (i >= 1441792) return;
  const float* src;
  int base;
  if (i < 262144) {
    if (i < 196608) { src = s_qkv; base = 0; }
    else            { src = s_proj; base = 196608; }
  } else if (i < 851968) {
    if (i < 655360) { src = s_gu; base = 262144; }
    else            { src = s_down; base = 655360; }
  } else {
    if (i < 1245184) { src = s_pgu; base = 851968; }
    else             { src = s_pdown; base = 1245184; }
  }
  f32x4 v = *(const f32x4*)(src + (size_t)(i - base) * 4);
  s16x4 o;
#pragma unroll
  for (int e = 0; e < 4; ++e) o[e] = f2bf(v[e]);
  *(s16x4*)(dst + (size_t)i * 4) = o;
}

__global__ __launch_bounds__(256) void prefix_cvt_kernel(const float* __restrict__ hs,
                                                         short* __restrict__ dst) {
  int i = blockIdx.x * 256 + threadIdx.x;
  if (i >= 512 * 128) return;
  int r = i >> 7, c4 = i & 127;
  int b = r >> 4, t = r & 15;
  f32x4 v = *(const f32x4*)(hs + ((size_t)b * 916 + t) * 512 + c4 * 4);
  s16x4 o;
#pragma unroll
  for (int e = 0; e < 4; ++e) o[e] = f2bf(v[e]);
  *(s16x4*)(dst + (size_t)r * 512 + c4 * 4) = o;
}

__global__ __launch_bounds__(512) void mean_kernel(const float* __restrict__ hs,
                                                   float* __restrict__ m) {
  int b = blockIdx.x, d = threadIdx.x;
  float s = 0.f;
#pragma unroll
  for (int t = 0; t < 16; ++t) s += hs[((size_t)b * 916 + t) * 512 + d];
  m[b * 512 + d] = s * (1.f / 16.f);
}

// grid = hs[:,16:] + mean -> bf16 window-partitioned xw ONLY (residual is
// re-read from xw by addnorm1 via the inverse mapping)
__global__ __launch_bounds__(256) void prep_kernel(const float* __restrict__ hs,
                                                   const float* __restrict__ m,
                                                   short* __restrict__ xw) {
  int idx = blockIdx.x * 256 + threadIdx.x;
  if (idx >= 32 * 900 * 128) return;
  int c4 = idx & 127;
  int row = idx >> 7;
  int b = row / 900, rem = row % 900;
  int gy = rem / 30, gx = rem % 30;
  f32x4 v = *(const f32x4*)(hs + ((size_t)b * 916 + 16 + rem) * 512 + c4 * 4);
  f32x4 mm = *(const f32x4*)(m + b * 512 + c4 * 4);
  v += mm;
  int ry = gy + 29; if (ry >= 30) ry -= 30;
  int rx = gx + 29; if (rx >= 30) rx -= 30;
  int wi = ry / 3, ii = ry % 3, wj = rx / 3, jj = rx % 3;
  size_t xrow = (size_t)((b * 100 + wi * 10 + wj) * 9 + ii * 3 + jj);
  s16x4 o;
#pragma unroll
  for (int e = 0; e < 4; ++e) o[e] = f2bf(v[e]);
  *(s16x4*)(xw + xrow * 512 + c4 * 4) = o;
}

// ---------------- windowed attention (9 tokens, 8 heads per window) ----------
__global__ __launch_bounds__(256) void attn_kernel(const short* __restrict__ qkv,
                                                   const float* __restrict__ rel_bias,
                                                   short* __restrict__ outp) {
  __shared__ short sq[9 * 512];
  __shared__ short sk[9 * 512];
  __shared__ short sv[9 * 512];
  __shared__ float sS[648];
  const int wlin = blockIdx.x;
  const int w = wlin % 100;
  const int wi = w / 10, wj = w % 10;
  const int tid = threadIdx.x;
  const short* base = qkv + (size_t)wlin * 9 * 1536;
  for (int idx = tid; idx < 1728; idx += 256) {
    int n = idx / 192, c8 = idx % 192;
    s16x8 v = *(const s16x8*)(base + (size_t)n * 1536 + c8 * 8);
    int which = c8 >> 6;
    short* dst = (which == 0) ? sq : (which == 1) ? sk : sv;
    *(s16x8*)(dst + n * 512 + (c8 & 63) * 8) = v;
  }
  __syncthreads();
  for (int idx = tid; idx < 648; idx += 256) {
    int h = idx / 81, r = idx % 81, i = r / 9, j = r % 9;
    const short* qp = sq + i * 512 + h * 64;
    const short* kp = sk + j * 512 + h * 64;
    float dot = 0.f;
#pragma unroll
    for (int c = 0; c < 8; ++c) {
      s16x8 qv = *(const s16x8*)(qp + c * 8);
      s16x8 kv = *(const s16x8*)(kp + c * 8);
#pragma unroll
      for (int e = 0; e < 8; ++e) dot += bf2f(qv[e]) * bf2f(kv[e]);
    }
    float s = dot * 0.125f;
    int ia = i / 3, ja = i % 3, ib = j / 3, jb = j % 3;
    s += rel_bias[(5 * (ia - ib + 2) + (ja - jb + 2)) * 8 + h];
    int ra = wi * 3 + ia, ca = wj * 3 + ja, rb = wi * 3 + ib, cb = wj * 3 + jb;
    int rga = (ra < 27) ? 0 : (ra < 29) ? 1 : 2;
    int cga = (ca < 27) ? 0 : (ca < 29) ? 1 : 2;
    int rgb = (rb < 27) ? 0 : (rb < 29) ? 1 : 2;
    int cgb = (cb < 27) ? 0 : (cb < 29) ? 1 : 2;
    if (rga * 3 + cga != rgb * 3 + cgb) s -= 100.f;
    sS[idx] = s;
  }
  __syncthreads();
  if (tid < 72) {
    float* row = sS + tid * 9;
    float mx = row[0];
#pragma unroll
    for (int j = 1; j < 9; ++j) mx = fmaxf(mx, row[j]);
    float e[9], sum = 0.f;
#pragma unroll
    for (int j = 0; j < 9; ++j) { e[j] = __expf(row[j] - mx); sum += e[j]; }
    float inv = 1.f / sum;
#pragma unroll
    for (int j = 0; j < 9; ++j) row[j] = e[j] * inv;
  }
  __syncthreads();
  for (int idx = tid; idx < 576; idx += 256) {
    int h = idx / 72, r = idx % 72, i = r / 8, d8 = r % 8;
    const float* p = sS + (h * 9 + i) * 9;
    float a[8] = {0, 0, 0, 0, 0, 0, 0, 0};
#pragma unroll
    for (int j = 0; j < 9; ++j) {
      float pj = p[j];
      s16x8 vv = *(const s16x8*)(sv + j * 512 + h * 64 + d8 * 8);
#pragma unroll
      for (int e = 0; e < 8; ++e) a[e] += pj * bf2f(vv[e]);
    }
    s16x8 o;
#pragma unroll
    for (int e = 0; e < 8; ++e) o[e] = f2bf(a[e]);
    *(s16x8*)(outp + ((size_t)wlin * 9 + i) * 512 + h * 64 + d8 * 8) = o;
  }
}

// ---------------- add + RMS norm (residual re-read from xw) ----------------
__global__ __launch_bounds__(64) void addnorm1_kernel(const short* __restrict__ xw,
                                                      const short* __restrict__ p,
                                                      float* __restrict__ out,
                                                      short* __restrict__ hsb) {
  int row = blockIdx.x, lane = threadIdx.x;  // row = b*900 + gy*30 + gx
  int b_ = row / 900, rem = row % 900;
  int gy = rem / 30, gx = rem % 30;
  int ry = gy + 29; if (ry >= 30) ry -= 30;
  int rx = gx + 29; if (rx >= 30) rx -= 30;
  size_t xrow = (size_t)((b_ * 100 + (ry / 3) * 10 + rx / 3) * 9 + (ry % 3) * 3 + rx % 3);
  s16x8 a8 = *(const s16x8*)(xw + xrow * 512 + lane * 8);
  s16x8 b8 = *(const s16x8*)(p + (size_t)row * 512 + lane * 8);
  float x[8];
  float ss = 0.f;
#pragma unroll
  for (int e = 0; e < 8; ++e) {
    x[e] = bf2f(a8[e]) + bf2f(b8[e]);
    ss += x[e] * x[e];
  }
  ss = wave_allsum(ss);
  float sc = rsqrtf(ss * (1.f / 512.f) + 1e-5f);
  size_t orow = ((size_t)b_ * 916 + 16 + rem) * 512 + lane * 8;
  s16x8 o;
#pragma unroll
  for (int e = 0; e < 8; ++e) {
    x[e] *= sc;
    o[e] = f2bf(x[e]);
  }
  *(f32x4*)(out + orow) = f32x4{x[0], x[1], x[2], x[3]};
  *(f32x4*)(out + orow + 4) = f32x4{x[4], x[5], x[6], x[7]};
  *(s16x8*)(hsb + orow) = o;
}

__global__ __launch_bounds__(64) void prefix_addnorm_kernel(const float* __restrict__ hs,
                                                            const short* __restrict__ pd,
                                                            float* __restrict__ out,
                                                            short* __restrict__ hsb) {
  int r = blockIdx.x, lane = threadIdx.x;
  int b = r >> 4, t = r & 15;
  size_t orow = ((size_t)b * 916 + t) * 512;
  f32x4 x[2];
  float ss = 0.f;
#pragma unroll
  for (int i = 0; i < 2; ++i) {
    f32x4 a = *(const f32x4*)(hs + orow + i * 256 + lane * 4);
    s16x4 d = *(const s16x4*)(pd + (size_t)r * 512 + i * 256 + lane * 4);
#pragma unroll
    for (int e = 0; e < 4; ++e) a[e] += bf2f(d[e]);
    x[i] = a;
    ss += a[0] * a[0] + a[1] * a[1] + a[2] * a[2] + a[3] * a[3];
  }
  ss = wave_allsum(ss);
  float sc = rsqrtf(ss * (1.f / 512.f) + 1e-5f);
#pragma unroll
  for (int i = 0; i < 2; ++i) {
    f32x4 y = x[i] * sc;
    *(f32x4*)(out + orow + i * 256 + lane * 4) = y;
    s16x4 o;
#pragma unroll
    for (int e = 0; e < 4; ++e) o[e] = f2bf(y[e]);
    *(s16x4*)(hsb + orow + i * 256 + lane * 4) = o;
  }
}

__global__ __launch_bounds__(64) void final_addnorm_kernel(float* __restrict__ io) {
  int row = blockIdx.x, lane = threadIdx.x;
  size_t off = (size_t)row * 512;
  f32x4 x[2];
  float ss = 0.f;
#pragma unroll
  for (int i = 0; i < 2; ++i) {
    f32x4 a = *(const f32x4*)(io + off + i * 256 + lane * 4);
    x[i] = a;
    ss += a[0] * a[0] + a[1] * a[1] + a[2] * a[2] + a[3] * a[3];
  }
  ss = wave_allsum(ss);
  float sc = rsqrtf(ss * (1.f / 512.f) + 1e-5f);
#pragma unroll
  for (int i = 0; i < 2; ++i)
    *(f32x4*)(io + off + i * 256 + lane * 4) = x[i] * sc;
}

// ---------------- workspace layout (bytes; liveness-overlaid) ----------------
// Peak 194.5 MB < proven >= 223.7 MB. Pads cover 256-row staging reads.
static constexpr size_t OFF_WQKV   = 0;         // contiguous weight region ...
static constexpr size_t OFF_WPROJ  = 1572864;
static constexpr size_t OFF_WGU    = 2097152;
static constexpr size_t OFF_WDOWN  = 5242880;
static constexpr size_t OFF_WPGU   = 6815744;
static constexpr size_t OFF_WPDOWN = 9961472;   // ... end 11534336
static constexpr size_t OFF_MEAN   = 11534336;
static constexpr size_t OFF_PREFB  = 11599872;
static constexpr size_t OFF_PINTER = 13697024;
static constexpr size_t OFF_PDOUT  = 15269888;  // end 15794176
static constexpr size_t OFF_XW     = 16777216;  // 28928*512*2 -> 46399488 (live 2..6)
static constexpr size_t OFF_QKV    = 46399488;  // 28800*1536*2 -> 134873088 (live 3..4)
static constexpr size_t OFF_ATTNO  = 134873088; // 28800*512*2 -> 164364288 (live 4..5)
static constexpr size_t OFF_PROJS  = OFF_QKV;   // reuse qkvb (dead after attn), live 5..6
static constexpr size_t OFF_INTER  = OFF_XW;    // reuse xw/projs/attno (dead), live 8
static constexpr size_t OFF_HSB    = 164364288; // 29440*512*2 -> 194510848 (live 6..8)

extern "C" void kernel_launch(void* const* d_in, const int* in_sizes, int n_in,
                              void* d_out, int out_size, void* d_ws, size_t ws_size,
                              hipStream_t stream) {
  const float* hs      = (const float*)d_in[0];
  const float* qkv_w   = (const float*)d_in[1];
  const float* qkv_b   = (const float*)d_in[2];
  const float* proj_w  = (const float*)d_in[3];
  const float* proj_b  = (const float*)d_in[4];
  const float* rel_b   = (const float*)d_in[5];
  const float* gu_w    = (const float*)d_in[6];
  const float* down_w  = (const float*)d_in[7];
  const float* pgu_w   = (const float*)d_in[8];
  const float* pdown_w = (const float*)d_in[9];

  char* ws = (char*)d_ws;
  short* Wqkv   = (short*)(ws + OFF_WQKV);
  short* Wproj  = (short*)(ws + OFF_WPROJ);
  short* Wgu    = (short*)(ws + OFF_WGU);
  short* Wdown  = (short*)(ws + OFF_WDOWN);
  short* Wpgu   = (short*)(ws + OFF_WPGU);
  short* Wpdown = (short*)(ws + OFF_WPDOWN);
  float* meanb  = (float*)(ws + OFF_MEAN);
  short* prefb  = (short*)(ws + OFF_PREFB);
  short* pinter = (short*)(ws + OFF_PINTER);
  short* pdout  = (short*)(ws + OFF_PDOUT);
  short* xw     = (short*)(ws + OFF_XW);
  short* qkvb   = (short*)(ws + OFF_QKV);
  short* attno  = (short*)(ws + OFF_ATTNO);
  short* projs  = (short*)(ws + OFF_PROJS);
  short* interb = (short*)(ws + OFF_INTER);
  short* hsb    = (short*)(ws + OFF_HSB);
  float* outf   = (float*)d_out;

  // 1. all weights fp32 -> bf16 (one kernel) + prefix rows
  cvt_all_kernel<<<5632, 256, 0, stream>>>(qkv_w, proj_w, gu_w, down_w,
                                           pgu_w, pdown_w, (short*)ws);
  prefix_cvt_kernel<<<256, 256, 0, stream>>>(hs, prefb);

  // 2. prefix mean -> windowed bf16 input
  mean_kernel<<<32, 512, 0, stream>>>(hs, meanb);
  prep_kernel<<<14400, 256, 0, stream>>>(hs, meanb, xw);

  // 3. QKV projection (M=28800, N=1536, K=512)
  gemm8<EPI_BIAS_BF16><<<dim3(6, 113), 512, 0, stream>>>(
      xw, Wqkv, qkv_b, qkvb, 28800, 1536, 512);
  // 4. windowed attention
  attn_kernel<<<3200, 256, 0, stream>>>(qkvb, rel_b, attno);

  // 5. output projection + scatter (N=512)
  gemm8<EPI_SCATTER><<<dim3(2, 113), 512, 0, stream>>>(
      attno, Wproj, proj_b, projs, 28800, 512, 512);
  // 6. x = rms(xw-residual + proj) -> fp32 d_out + bf16 hsb
  addnorm1_kernel<<<28800, 64, 0, stream>>>(xw, projs, outf, hsb);

  // 7. prefix branch (small): 2-phase gemms + rms
  gemm2<EPI_GU><<<dim3(24, 4), 256, 0, stream>>>(
      prefb, Wpgu, Wpgu + 1536 * 512, nullptr, pinter, 512, 1536, 512);
  gemm2<EPI_BF16><<<dim3(4, 4), 256, 0, stream>>>(
      pinter, Wpdown, nullptr, nullptr, pdout, 512, 512, 1536);
  prefix_addnorm_kernel<<<512, 64, 0, stream>>>(hs, pdout, outf, hsb);

  // 8. full-sequence fused swiglu (M=29312); down adds into d_out fp32
  gemm8gu<<<dim3(12, 115), 512, 0, stream>>>(
      hsb, Wgu, Wgu + 1536 * 512, interb, 29312, 512);
  gemm8<EPI_ADDOUT><<<dim3(2, 115), 512, 0, stream>>>(
      interb, Wdown, nullptr, outf, 29312, 512, 1536);
  // 9. out = rms(out) in place
  final_addnorm_kernel<<<29312, 64, 0, stream>>>(outf);

  (void)in_sizes; (void)n_in; (void)out_size; (void)ws_size;
}

// Round 7
// 425.742 us; speedup vs baseline: 1.3499x; 1.0364x over previous
//
#include <hip/hip_runtime.h>
#include <cstdint>
#include <cstddef>

typedef float f32x4 __attribute__((ext_vector_type(4)));
typedef short s16x8 __attribute__((ext_vector_type(8)));
typedef short s16x4 __attribute__((ext_vector_type(4)));

#define DEV static __device__ __forceinline__

DEV float bf2f(short s) {
  union { unsigned u; float f; } c;
  c.u = ((unsigned)(unsigned short)s) << 16;
  return c.f;
}
DEV short f2bf(float f) {
  union { float f; unsigned u; } c;
  c.f = f;
  unsigned r = c.u + 0x7fffu + ((c.u >> 16) & 1u);
  return (short)(r >> 16);
}
DEV float wave_allsum(float v) {
#pragma unroll
  for (int off = 32; off > 0; off >>= 1) v += __shfl_xor(v, off, 64);
  return v;
}
DEV void gload_lds16(const void* g, void* l) {
  __builtin_amdgcn_global_load_lds(
      (const __attribute__((address_space(1))) void*)g,
      (__attribute__((address_space(3))) void*)l, 16, 0, 0);
}
DEV float silu_f(float g) { return g / (1.f + __expf(-g)); }

// bijective XCD-chunk swizzle (m204)
DEV int xcd_swizzle(int orig, int nwg) {
  int q = nwg >> 3, r = nwg & 7;
  int xcd = orig & 7, pos = orig >> 3;
  return (xcd < r ? xcd * (q + 1) : r * (q + 1) + (xcd - r) * q) + pos;
}

DEV void sync_phase() {
  asm volatile("s_waitcnt vmcnt(0)" ::: "memory");
  __builtin_amdgcn_s_barrier();
  __builtin_amdgcn_sched_barrier(0);
}

enum { EPI_BF16 = 0, EPI_BIAS_BF16 = 1, EPI_SCATTER = 4, EPI_GU = 6 };

// ================= 8-phase 256x256 bf16 GEMM (QKV / proj / down) =========
template <int EPI>
__global__ __launch_bounds__(512, 2) void gemm8(
    const short* __restrict__ A, const short* __restrict__ W,
    const float* __restrict__ bias, void* __restrict__ outp,
    int M, int N, int K)
{
  __shared__ short lds[65536];  // 128 KiB
  const int tid = threadIdx.x;
  const int wid = tid >> 6, lane = tid & 63;
  const int wr = wid >> 2, wc = wid & 3;
  const int nwg = gridDim.x * gridDim.y;
  const int orig = blockIdx.y * gridDim.x + blockIdx.x;
  const int wg = xcd_swizzle(orig, nwg);
  const int bx = wg % gridDim.x, by = wg / gridDim.x;
  const int row0 = by * 256;
  const int c0 = bx * 256;

  f32x4 acc[8][4];
#pragma unroll
  for (int m = 0; m < 8; ++m)
#pragma unroll
    for (int n = 0; n < 4; ++n) acc[m][n] = f32x4{0.f, 0.f, 0.f, 0.f};

  const int srow = tid >> 3;
  const int k8s = (tid & 7) ^ (srow & 7);
  const short* aub[4];
  const short* bub[4];
#pragma unroll
  for (int u = 0; u < 4; ++u) {
    aub[u] = A + (size_t)(row0 + u * 64 + srow) * K + k8s * 8;
    bub[u] = W + (size_t)(c0 + u * 64 + srow) * K + k8s * 8;
  }
  const int ldw = wid * 512;

#define SA(d, u, kt) gload_lds16(aub[u] + (kt), &lds[(d)*16384 + (u)*4096 + ldw])
#define SB(d, u, kt) gload_lds16(bub[u] + (kt), &lds[32768 + (d)*16384 + (u)*4096 + ldw])
#define GATE(VN)                                              \
  asm volatile("s_waitcnt vmcnt(" #VN ")" ::: "memory");      \
  __builtin_amdgcn_s_barrier();                               \
  __builtin_amdgcn_sched_barrier(0);

  const int kg0 = (lane >> 4) ^ (lane & 7);
  const int kg1 = (4 + (lane >> 4)) ^ (lane & 7);
  const int aoff = (wr * 128 + (lane & 15)) * 64;
  const int boff = 32768 + (wc * 64 + (lane & 15)) * 64;

#define READ_B(d)                                                              \
  _Pragma("unroll") for (int n = 0; n < 4; ++n) {                              \
    bfr[0][n] = *(const s16x8*)&lds[(d)*16384 + boff + n * 1024 + kg0 * 8];    \
    bfr[1][n] = *(const s16x8*)&lds[(d)*16384 + boff + n * 1024 + kg1 * 8];    \
  }
#define DO_PHASE(d, p)                                                         \
  do {                                                                         \
    s16x8 a00 = *(const s16x8*)&lds[(d)*16384 + aoff + (2*(p))*1024 + kg0*8];  \
    s16x8 a01 = *(const s16x8*)&lds[(d)*16384 + aoff + (2*(p))*1024 + kg1*8];  \
    s16x8 a10 = *(const s16x8*)&lds[(d)*16384 + aoff + (2*(p)+1)*1024 + kg0*8];\
    s16x8 a11 = *(const s16x8*)&lds[(d)*16384 + aoff + (2*(p)+1)*1024 + kg1*8];\
    __builtin_amdgcn_s_setprio(1);                                             \
    _Pragma("unroll") for (int n = 0; n < 4; ++n)                              \
      acc[2*(p)][n] = __builtin_amdgcn_mfma_f32_16x16x32_bf16(a00, bfr[0][n], acc[2*(p)][n], 0, 0, 0); \
    _Pragma("unroll") for (int n = 0; n < 4; ++n)                              \
      acc[2*(p)+1][n] = __builtin_amdgcn_mfma_f32_16x16x32_bf16(a10, bfr[0][n], acc[2*(p)+1][n], 0, 0, 0); \
    _Pragma("unroll") for (int n = 0; n < 4; ++n)                              \
      acc[2*(p)][n] = __builtin_amdgcn_mfma_f32_16x16x32_bf16(a01, bfr[1][n], acc[2*(p)][n], 0, 0, 0); \
    _Pragma("unroll") for (int n = 0; n < 4; ++n)                              \
      acc[2*(p)+1][n] = __builtin_amdgcn_mfma_f32_16x16x32_bf16(a11, bfr[1][n], acc[2*(p)+1][n], 0, 0, 0); \
    __builtin_amdgcn_s_setprio(0);                                             \
  } while (0)

  SB(0, 0, 0); SB(0, 1, 0); SB(0, 2, 0); SB(0, 3, 0);
  SA(0, 0, 0); SA(0, 2, 0); SA(0, 1, 0); SA(0, 3, 0);

  const int NT = K >> 6;
  for (int t = 0; t < NT - 1; ++t) {
    const int d = t & 1, d1 = d ^ 1;
    const int kn = (t + 1) * 64;
    s16x8 bfr[2][4];
    SB(d1, 0, kn); SB(d1, 1, kn);
    GATE(4);
    READ_B(d);
    DO_PHASE(d, 0);
    SB(d1, 2, kn); SB(d1, 3, kn);
    DO_PHASE(d, 1);
    SA(d1, 0, kn); SA(d1, 2, kn);
    GATE(6);
    DO_PHASE(d, 2);
    SA(d1, 1, kn); SA(d1, 3, kn);
    DO_PHASE(d, 3);
  }
  {
    const int d = (NT - 1) & 1;
    s16x8 bfr[2][4];
    GATE(2);
    READ_B(d);
    DO_PHASE(d, 0);
    DO_PHASE(d, 1);
    GATE(0);
    DO_PHASE(d, 2);
    DO_PHASE(d, 3);
  }
#undef SA
#undef SB
#undef READ_B
#undef DO_PHASE

  const int li = lane >> 4, lc = lane & 15;
#pragma unroll
  for (int m = 0; m < 8; ++m) {
#pragma unroll
    for (int i = 0; i < 4; ++i) {
      int gr = row0 + wr * 128 + m * 16 + li * 4 + i;
      if (gr >= M) continue;
      size_t orow;
      if (EPI == EPI_SCATTER) {
        int b = gr / 900, rem = gr % 900;
        int w = rem / 9, n_ = rem % 9;
        int wi = w / 10, wj = w % 10;
        int ii = n_ / 3, jj = n_ % 3;
        int gy = wi * 3 + ii + 1; if (gy >= 30) gy -= 30;
        int gx = wj * 3 + jj + 1; if (gx >= 30) gx -= 30;
        orow = (size_t)b * 900 + gy * 30 + gx;
      } else {
        orow = (size_t)gr;
      }
#pragma unroll
      for (int n = 0; n < 4; ++n) {
        int gc = c0 + wc * 64 + n * 16 + lc;
        float v = acc[m][n][i];
        if (EPI == EPI_BIAS_BF16 || EPI == EPI_SCATTER) v += bias[gc];
        ((short*)outp)[orow * (size_t)N + gc] = f2bf(v);
      }
    }
  }
}

// ============ GU GEMM v3: A-frags read ONCE, reused for gate AND up ========
// Wave (wr 0..3, wc 0..1): rows wr*64..+63, cols wc*64..+63 (gate & up).
// Per tile: GATE(2) -> read B-gate(8) + A(8) -> 32 gate MFMA (stage A0-3 of
// next tile between halves) -> GATE(4) -> read B-up(8) -> 32 up MFMA (stage
// B0-3). Queue invariant at GATE(2): [A0-3,B0-3]=8, wait<=2 retires A0-3,B0,B1;
// at GATE(4): [B2,B3, A0-3(next)]=6, wait<=4 retires B2,B3. LDS reads/tile/wave
// 24 (was 32). waitcnt precedes barrier -> cross-wave slice completion sound.
__global__ __launch_bounds__(512, 2) void gemm8gu(
    const short* __restrict__ A, const short* __restrict__ Wg,
    const short* __restrict__ Wu, short* __restrict__ outp, int M, int K)
{
  __shared__ short lds[65536];
  const int tid = threadIdx.x;
  const int wid = tid >> 6, lane = tid & 63;
  const int wr = wid >> 1, wc = wid & 1;
  const int nwg = gridDim.x * gridDim.y;
  const int orig = blockIdx.y * gridDim.x + blockIdx.x;
  const int wg = xcd_swizzle(orig, nwg);
  const int bx = wg % gridDim.x, by = wg / gridDim.x;
  const int row0 = by * 256;
  const int colg = bx * 128;

  f32x4 accg[4][4], accu[4][4];
#pragma unroll
  for (int m = 0; m < 4; ++m)
#pragma unroll
    for (int n = 0; n < 4; ++n) {
      accg[m][n] = f32x4{0.f, 0.f, 0.f, 0.f};
      accu[m][n] = f32x4{0.f, 0.f, 0.f, 0.f};
    }

  const int srow = tid >> 3;
  const int k8s = (tid & 7) ^ (srow & 7);
  const short* aub[4];
  const short* bub[4];
#pragma unroll
  for (int u = 0; u < 4; ++u)
    aub[u] = A + (size_t)(row0 + u * 64 + srow) * K + k8s * 8;
#pragma unroll
  for (int u = 0; u < 2; ++u) {
    bub[u]     = Wg + (size_t)(colg + u * 64 + srow) * K + k8s * 8;
    bub[u + 2] = Wu + (size_t)(colg + u * 64 + srow) * K + k8s * 8;
  }
  const int ldw = wid * 512;

#define SA(d, u, kt) gload_lds16(aub[u] + (kt), &lds[(d)*16384 + (u)*4096 + ldw])
#define SB(d, u, kt) gload_lds16(bub[u] + (kt), &lds[32768 + (d)*16384 + (u)*4096 + ldw])
#define GATE(VN)                                              \
  asm volatile("s_waitcnt vmcnt(" #VN ")" ::: "memory");      \
  __builtin_amdgcn_s_barrier();                               \
  __builtin_amdgcn_sched_barrier(0);

  const int kg0 = (lane >> 4) ^ (lane & 7);
  const int kg1 = (4 + (lane >> 4)) ^ (lane & 7);
  const int aoff = (wr * 64 + (lane & 15)) * 64;
  const int bgoff = 32768 + (wc * 64 + (lane & 15)) * 64;
  const int buoff = 32768 + (128 + wc * 64 + (lane & 15)) * 64;

#define READ_BF(d, BOFF, BF)                                                   \
  _Pragma("unroll") for (int n = 0; n < 4; ++n) {                              \
    BF[0][n] = *(const s16x8*)&lds[(d)*16384 + (BOFF) + n * 1024 + kg0 * 8];   \
    BF[1][n] = *(const s16x8*)&lds[(d)*16384 + (BOFF) + n * 1024 + kg1 * 8];   \
  }
#define READ_A(d)                                                              \
  _Pragma("unroll") for (int m = 0; m < 4; ++m) {                              \
    af[0][m] = *(const s16x8*)&lds[(d)*16384 + aoff + m * 1024 + kg0 * 8];     \
    af[1][m] = *(const s16x8*)&lds[(d)*16384 + aoff + m * 1024 + kg1 * 8];     \
  }
#define MM2(BF, h, ACC)                                                        \
  do {                                                                         \
    __builtin_amdgcn_s_setprio(1);                                             \
    _Pragma("unroll") for (int n = 0; n < 4; ++n)                              \
      ACC[2*(h)][n] = __builtin_amdgcn_mfma_f32_16x16x32_bf16(af[0][2*(h)], BF[0][n], ACC[2*(h)][n], 0, 0, 0); \
    _Pragma("unroll") for (int n = 0; n < 4; ++n)                              \
      ACC[2*(h)+1][n] = __builtin_amdgcn_mfma_f32_16x16x32_bf16(af[0][2*(h)+1], BF[0][n], ACC[2*(h)+1][n], 0, 0, 0); \
    _Pragma("unroll") for (int n = 0; n < 4; ++n)                              \
      ACC[2*(h)][n] = __builtin_amdgcn_mfma_f32_16x16x32_bf16(af[1][2*(h)], BF[1][n], ACC[2*(h)][n], 0, 0, 0); \
    _Pragma("unroll") for (int n = 0; n < 4; ++n)                              \
      ACC[2*(h)+1][n] = __builtin_amdgcn_mfma_f32_16x16x32_bf16(af[1][2*(h)+1], BF[1][n], ACC[2*(h)+1][n], 0, 0, 0); \
    __builtin_amdgcn_s_setprio(0);                                             \
  } while (0)

  // prologue: tile 0 into buf 0: A0..A3, B0..B3
  SA(0, 0, 0); SA(0, 1, 0); SA(0, 2, 0); SA(0, 3, 0);
  SB(0, 0, 0); SB(0, 1, 0); SB(0, 2, 0); SB(0, 3, 0);

  const int NT = K >> 6;
  for (int t = 0; t < NT - 1; ++t) {
    const int d = t & 1, d1 = d ^ 1;
    const int kn = (t + 1) * 64;
    s16x8 af[2][4], bg[2][4], bu[2][4];
    GATE(2);                       // A0-3,B0,B1 of tile t complete
    READ_BF(d, bgoff, bg);
    READ_A(d);
    MM2(bg, 0, accg);
    SA(d1, 0, kn); SA(d1, 1, kn);
    MM2(bg, 1, accg);
    SA(d1, 2, kn); SA(d1, 3, kn);
    GATE(4);                       // B2,B3 of tile t complete
    READ_BF(d, buoff, bu);
    MM2(bu, 0, accu);
    SB(d1, 0, kn); SB(d1, 1, kn);
    MM2(bu, 1, accu);
    SB(d1, 2, kn); SB(d1, 3, kn);
  }
  {
    const int d = (NT - 1) & 1;
    s16x8 af[2][4], bg[2][4], bu[2][4];
    GATE(2);
    READ_BF(d, bgoff, bg);
    READ_A(d);
    MM2(bg, 0, accg);
    MM2(bg, 1, accg);
    GATE(0);
    READ_BF(d, buoff, bu);
    MM2(bu, 0, accu);
    MM2(bu, 1, accu);
  }
#undef SA
#undef SB
#undef READ_BF
#undef READ_A
#undef MM2
#undef GATE

  const int li = lane >> 4, lc = lane & 15;
#pragma unroll
  for (int m = 0; m < 4; ++m) {
#pragma unroll
    for (int i = 0; i < 4; ++i) {
      int gr = row0 + wr * 64 + m * 16 + li * 4 + i;
      if (gr >= M) continue;
#pragma unroll
      for (int n = 0; n < 4; ++n) {
        int gc = colg + wc * 64 + n * 16 + lc;
        outp[(size_t)gr * 1536 + gc] = f2bf(silu_f(accg[m][n][i]) * accu[m][n][i]);
      }
    }
  }
}

// ================= 2-phase 128x128 GEMM (small prefix GEMMs) =====
template <int EPI>
__global__ __launch_bounds__(256) void gemm2(
    const short* __restrict__ A, const short* __restrict__ W,
    const short* __restrict__ Wu, const float* __restrict__ bias,
    void* __restrict__ outp, int M, int N, int K)
{
  __shared__ short As0[8192], Bs0[8192];
  __shared__ short As1[8192], Bs1[8192];
  const int tid = threadIdx.x;
  const int wave = tid >> 6, lane = tid & 63;
  const int nwg = gridDim.x * gridDim.y;
  const int orig = blockIdx.y * gridDim.x + blockIdx.x;
  const int wg = xcd_swizzle(orig, nwg);
  const int bx = wg % gridDim.x, by = wg / gridDim.x;
  const int row0 = by * 128;
  const int col0 = (EPI == EPI_GU) ? bx * 64 : bx * 128;
  const int wr = wave >> 1, wc = wave & 1;

  f32x4 acc[4][4];
#pragma unroll
  for (int m = 0; m < 4; ++m)
#pragma unroll
    for (int n = 0; n < 4; ++n) acc[m][n] = f32x4{0.f, 0.f, 0.f, 0.f};

  const short* aptr[4];
  const short* bptr[4];
  int ldst[4];
#pragma unroll
  for (int i = 0; i < 4; ++i) {
    int e = i * 2048 + tid * 8;
    int srow = e >> 6;
    int skg = ((e >> 3) & 7) ^ (srow & 7);
    aptr[i] = A + (size_t)(row0 + srow) * K + skg * 8;
    if (EPI == EPI_GU)
      bptr[i] = (srow < 64 ? W + (size_t)(col0 + srow) * K
                           : Wu + (size_t)(col0 + srow - 64) * K) + skg * 8;
    else
      bptr[i] = W + (size_t)(col0 + srow) * K + skg * 8;
    ldst[i] = i * 2048 + wave * 512;
  }

#define STAGE(AS, BS, KT)                                   \
  do {                                                      \
    _Pragma("unroll") for (int i = 0; i < 4; ++i)           \
        gload_lds16(aptr[i] + (KT), &AS[ldst[i]]);          \
    _Pragma("unroll") for (int i = 0; i < 4; ++i)           \
        gload_lds16(bptr[i] + (KT), &BS[ldst[i]]);          \
  } while (0)

#define COMPUTE(AS, BS)                                                        \
  do {                                                                         \
    _Pragma("unroll") for (int ks = 0; ks < 2; ++ks) {                         \
      s16x8 af[4], bfr[4];                                                     \
      _Pragma("unroll") for (int m = 0; m < 4; ++m) {                          \
        int row = wr * 64 + m * 16 + (lane & 15);                              \
        int kg = (ks * 4 + (lane >> 4)) ^ (row & 7);                           \
        af[m] = *(const s16x8*)&AS[row * 64 + kg * 8];                         \
      }                                                                        \
      _Pragma("unroll") for (int n = 0; n < 4; ++n) {                          \
        int brow = (EPI == EPI_GU)                                             \
                       ? ((n < 2 ? wc * 32 + n * 16                            \
                                 : 64 + wc * 32 + (n - 2) * 16) + (lane & 15)) \
                       : (wc * 64 + n * 16 + (lane & 15));                     \
        int kg = (ks * 4 + (lane >> 4)) ^ (brow & 7);                          \
        bfr[n] = *(const s16x8*)&BS[brow * 64 + kg * 8];                       \
      }                                                                        \
      _Pragma("unroll") for (int m = 0; m < 4; ++m)                            \
          _Pragma("unroll") for (int n = 0; n < 4; ++n)                        \
              acc[m][n] = __builtin_amdgcn_mfma_f32_16x16x32_bf16(             \
                  af[m], bfr[n], acc[m][n], 0, 0, 0);                          \
    }                                                                          \
  } while (0)

  STAGE(As0, Bs0, 0);
  sync_phase();
  for (int kt = 0; kt < K; kt += 128) {
    STAGE(As1, Bs1, kt + 64);
    COMPUTE(As0, Bs0);
    sync_phase();
    if (kt + 128 < K) STAGE(As0, Bs0, kt + 128);
    COMPUTE(As1, Bs1);
    if (kt + 128 < K) sync_phase();
  }
#undef STAGE
#undef COMPUTE

  const int lr = (lane >> 4) * 4, lc = lane & 15;
#pragma unroll
  for (int m = 0; m < 4; ++m) {
#pragma unroll
    for (int i = 0; i < 4; ++i) {
      int gr = row0 + wr * 64 + m * 16 + lr + i;
      if (EPI == EPI_GU) {
#pragma unroll
        for (int n = 0; n < 2; ++n) {
          int gc = col0 + wc * 32 + n * 16 + lc;
          float v = silu_f(acc[m][n][i]) * acc[m][n + 2][i];
          ((short*)outp)[(size_t)gr * N + gc] = f2bf(v);
        }
      } else {
#pragma unroll
        for (int n = 0; n < 4; ++n) {
          int gc = col0 + wc * 64 + n * 16 + lc;
          ((short*)outp)[(size_t)gr * N + gc] = f2bf(acc[m][n][i]);
        }
      }
    }
  }
}

// ---------------- fused weight conversion (dst region is contiguous) --------
__global__ __launch_bounds__(256) void cvt_all_kernel(
    const float* __restrict__ s_qkv, const float* __restrict__ s_proj,
    const float* __restrict__ s_gu, const float* __restrict__ s_down,
    const float* __restrict__ s_pgu, const float* __restrict__ s_pdown,
    short* __restrict__ dst) {
  int i = blockIdx.x * 256 + threadIdx.x;
  if (i >= 1441792) return;
  const float* src;
  int base;
  if (i < 262144) {
    if (i < 196608) { src = s_qkv; base = 0; }
    else            { src = s_proj; base = 196608; }
  } else if (i < 851968) {
    if (i < 655360) { src = s_gu; base = 262144; }
    else            { src = s_down; base = 655360; }
  } else {
    if (i < 1245184) { src = s_pgu; base = 851968; }
    else             { src = s_pdown; base = 1245184; }
  }
  f32x4 v = *(const f32x4*)(src + (size_t)(i - base) * 4);
  s16x4 o;
#pragma unroll
  for (int e = 0; e < 4; ++e) o[e] = f2bf(v[e]);
  *(s16x4*)(dst + (size_t)i * 4) = o;
}

__global__ __launch_bounds__(256) void prefix_cvt_kernel(const float* __restrict__ hs,
                                                         short* __restrict__ dst) {
  int i = blockIdx.x * 256 + threadIdx.x;
  if (i >= 512 * 128) return;
  int r = i >> 7, c4 = i & 127;
  int b = r >> 4, t = r & 15;
  f32x4 v = *(const f32x4*)(hs + ((size_t)b * 916 + t) * 512 + c4 * 4);
  s16x4 o;
#pragma unroll
  for (int e = 0; e < 4; ++e) o[e] = f2bf(v[e]);
  *(s16x4*)(dst + (size_t)r * 512 + c4 * 4) = o;
}

__global__ __launch_bounds__(512) void mean_kernel(const float* __restrict__ hs,
                                                   float* __restrict__ m) {
  int b = blockIdx.x, d = threadIdx.x;
  float s = 0.f;
#pragma unroll
  for (int t = 0; t < 16; ++t) s += hs[((size_t)b * 916 + t) * 512 + d];
  m[b * 512 + d] = s * (1.f / 16.f);
}

// grid = hs[:,16:] + mean -> bf16 window-partitioned xw ONLY
__global__ __launch_bounds__(256) void prep_kernel(const float* __restrict__ hs,
                                                   const float* __restrict__ m,
                                                   short* __restrict__ xw) {
  int idx = blockIdx.x * 256 + threadIdx.x;
  if (idx >= 32 * 900 * 128) return;
  int c4 = idx & 127;
  int row = idx >> 7;
  int b = row / 900, rem = row % 900;
  int gy = rem / 30, gx = rem % 30;
  f32x4 v = *(const f32x4*)(hs + ((size_t)b * 916 + 16 + rem) * 512 + c4 * 4);
  f32x4 mm = *(const f32x4*)(m + b * 512 + c4 * 4);
  v += mm;
  int ry = gy + 29; if (ry >= 30) ry -= 30;
  int rx = gx + 29; if (rx >= 30) rx -= 30;
  int wi = ry / 3, ii = ry % 3, wj = rx / 3, jj = rx % 3;
  size_t xrow = (size_t)((b * 100 + wi * 10 + wj) * 9 + ii * 3 + jj);
  s16x4 o;
#pragma unroll
  for (int e = 0; e < 4; ++e) o[e] = f2bf(v[e]);
  *(s16x4*)(xw + xrow * 512 + c4 * 4) = o;
}

// ---------------- windowed attention (9 tokens, 8 heads per window) ----------
__global__ __launch_bounds__(256) void attn_kernel(const short* __restrict__ qkv,
                                                   const float* __restrict__ rel_bias,
                                                   short* __restrict__ outp) {
  __shared__ short sq[9 * 512];
  __shared__ short sk[9 * 512];
  __shared__ short sv[9 * 512];
  __shared__ float sS[648];
  const int wlin = blockIdx.x;
  const int w = wlin % 100;
  const int wi = w / 10, wj = w % 10;
  const int tid = threadIdx.x;
  const short* base = qkv + (size_t)wlin * 9 * 1536;
  for (int idx = tid; idx < 1728; idx += 256) {
    int n = idx / 192, c8 = idx % 192;
    s16x8 v = *(const s16x8*)(base + (size_t)n * 1536 + c8 * 8);
    int which = c8 >> 6;
    short* dst = (which == 0) ? sq : (which == 1) ? sk : sv;
    *(s16x8*)(dst + n * 512 + (c8 & 63) * 8) = v;
  }
  __syncthreads();
  for (int idx = tid; idx < 648; idx += 256) {
    int h = idx / 81, r = idx % 81, i = r / 9, j = r % 9;
    const short* qp = sq + i * 512 + h * 64;
    const short* kp = sk + j * 512 + h * 64;
    float dot = 0.f;
#pragma unroll
    for (int c = 0; c < 8; ++c) {
      s16x8 qv = *(const s16x8*)(qp + c * 8);
      s16x8 kv = *(const s16x8*)(kp + c * 8);
#pragma unroll
      for (int e = 0; e < 8; ++e) dot += bf2f(qv[e]) * bf2f(kv[e]);
    }
    float s = dot * 0.125f;
    int ia = i / 3, ja = i % 3, ib = j / 3, jb = j % 3;
    s += rel_bias[(5 * (ia - ib + 2) + (ja - jb + 2)) * 8 + h];
    int ra = wi * 3 + ia, ca = wj * 3 + ja, rb = wi * 3 + ib, cb = wj * 3 + jb;
    int rga = (ra < 27) ? 0 : (ra < 29) ? 1 : 2;
    int cga = (ca < 27) ? 0 : (ca < 29) ? 1 : 2;
    int rgb = (rb < 27) ? 0 : (rb < 29) ? 1 : 2;
    int cgb = (cb < 27) ? 0 : (cb < 29) ? 1 : 2;
    if (rga * 3 + cga != rgb * 3 + cgb) s -= 100.f;
    sS[idx] = s;
  }
  __syncthreads();
  if (tid < 72) {
    float* row = sS + tid * 9;
    float mx = row[0];
#pragma unroll
    for (int j = 1; j < 9; ++j) mx = fmaxf(mx, row[j]);
    float e[9], sum = 0.f;
#pragma unroll
    for (int j = 0; j < 9; ++j) { e[j] = __expf(row[j] - mx); sum += e[j]; }
    float inv = 1.f / sum;
#pragma unroll
    for (int j = 0; j < 9; ++j) row[j] = e[j] * inv;
  }
  __syncthreads();
  for (int idx = tid; idx < 576; idx += 256) {
    int h = idx / 72, r = idx % 72, i = r / 8, d8 = r % 8;
    const float* p = sS + (h * 9 + i) * 9;
    float a[8] = {0, 0, 0, 0, 0, 0, 0, 0};
#pragma unroll
    for (int j = 0; j < 9; ++j) {
      float pj = p[j];
      s16x8 vv = *(const s16x8*)(sv + j * 512 + h * 64 + d8 * 8);
#pragma unroll
      for (int e = 0; e < 8; ++e) a[e] += pj * bf2f(vv[e]);
    }
    s16x8 o;
#pragma unroll
    for (int e = 0; e < 8; ++e) o[e] = f2bf(a[e]);
    *(s16x8*)(outp + ((size_t)wlin * 9 + i) * 512 + h * 64 + d8 * 8) = o;
  }
}

// ---------------- add + RMS norm (4 rows per 256-thread block) -------------
__global__ __launch_bounds__(256) void addnorm1_kernel(const short* __restrict__ xw,
                                                       const short* __restrict__ p,
                                                       float* __restrict__ out,
                                                       short* __restrict__ hsb) {
  int row = blockIdx.x * 4 + (threadIdx.x >> 6);
  int lane = threadIdx.x & 63;
  int b_ = row / 900, rem = row % 900;
  int gy = rem / 30, gx = rem % 30;
  int ry = gy + 29; if (ry >= 30) ry -= 30;
  int rx = gx + 29; if (rx >= 30) rx -= 30;
  size_t xrow = (size_t)((b_ * 100 + (ry / 3) * 10 + rx / 3) * 9 + (ry % 3) * 3 + rx % 3);
  s16x8 a8 = *(const s16x8*)(xw + xrow * 512 + lane * 8);
  s16x8 b8 = *(const s16x8*)(p + (size_t)row * 512 + lane * 8);
  float x[8];
  float ss = 0.f;
#pragma unroll
  for (int e = 0; e < 8; ++e) {
    x[e] = bf2f(a8[e]) + bf2f(b8[e]);
    ss += x[e] * x[e];
  }
  ss = wave_allsum(ss);
  float sc = rsqrtf(ss * (1.f / 512.f) + 1e-5f);
  size_t orow = ((size_t)b_ * 916 + 16 + rem) * 512 + lane * 8;
  s16x8 o;
#pragma unroll
  for (int e = 0; e < 8; ++e) {
    x[e] *= sc;
    o[e] = f2bf(x[e]);
  }
  *(f32x4*)(out + orow) = f32x4{x[0], x[1], x[2], x[3]};
  *(f32x4*)(out + orow + 4) = f32x4{x[4], x[5], x[6], x[7]};
  *(s16x8*)(hsb + orow) = o;
}

__global__ __launch_bounds__(256) void prefix_addnorm_kernel(const float* __restrict__ hs,
                                                             const short* __restrict__ pd,
                                                             float* __restrict__ out,
                                                             short* __restrict__ hsb) {
  int r = blockIdx.x * 4 + (threadIdx.x >> 6);
  int lane = threadIdx.x & 63;
  int b = r >> 4, t = r & 15;
  size_t orow = ((size_t)b * 916 + t) * 512 + lane * 8;
  f32x4 a0 = *(const f32x4*)(hs + orow);
  f32x4 a1 = *(const f32x4*)(hs + orow + 4);
  s16x8 d8 = *(const s16x8*)(pd + (size_t)r * 512 + lane * 8);
  float x[8];
  float ss = 0.f;
#pragma unroll
  for (int e = 0; e < 8; ++e) {
    x[e] = (e < 4 ? a0[e] : a1[e - 4]) + bf2f(d8[e]);
    ss += x[e] * x[e];
  }
  ss = wave_allsum(ss);
  float sc = rsqrtf(ss * (1.f / 512.f) + 1e-5f);
  s16x8 o;
#pragma unroll
  for (int e = 0; e < 8; ++e) {
    x[e] *= sc;
    o[e] = f2bf(x[e]);
  }
  *(f32x4*)(out + orow) = f32x4{x[0], x[1], x[2], x[3]};
  *(f32x4*)(out + orow + 4) = f32x4{x[4], x[5], x[6], x[7]};
  *(s16x8*)(hsb + orow) = o;
}

// out = rms(io + dn): io holds fp32 hs, dn holds bf16 down-proj
__global__ __launch_bounds__(256) void final_addnorm_kernel(const short* __restrict__ dn,
                                                            float* __restrict__ io) {
  int row = blockIdx.x * 4 + (threadIdx.x >> 6);
  int lane = threadIdx.x & 63;
  size_t off = (size_t)row * 512 + lane * 8;
  f32x4 a0 = *(const f32x4*)(io + off);
  f32x4 a1 = *(const f32x4*)(io + off + 4);
  s16x8 d8 = *(const s16x8*)(dn + off);
  float x[8];
  float ss = 0.f;
#pragma unroll
  for (int e = 0; e < 8; ++e) {
    x[e] = (e < 4 ? a0[e] : a1[e - 4]) + bf2f(d8[e]);
    ss += x[e] * x[e];
  }
  ss = wave_allsum(ss);
  float sc = rsqrtf(ss * (1.f / 512.f) + 1e-5f);
#pragma unroll
  for (int e = 0; e < 8; ++e) x[e] *= sc;
  *(f32x4*)(io + off) = f32x4{x[0], x[1], x[2], x[3]};
  *(f32x4*)(io + off + 4) = f32x4{x[4], x[5], x[6], x[7]};
}

// ---------------- workspace layout (bytes; liveness-overlaid) ----------------
// Peak < 194.5 MB < proven >= 223.7 MB. Pads cover 256-row staging reads.
static constexpr size_t OFF_WQKV   = 0;         // contiguous weight region ...
static constexpr size_t OFF_WPROJ  = 1572864;
static constexpr size_t OFF_WGU    = 2097152;
static constexpr size_t OFF_WDOWN  = 5242880;
static constexpr size_t OFF_WPGU   = 6815744;
static constexpr size_t OFF_WPDOWN = 9961472;   // ... end 11534336
static constexpr size_t OFF_MEAN   = 11534336;
static constexpr size_t OFF_PREFB  = 11599872;
static constexpr size_t OFF_PINTER = 13697024;
static constexpr size_t OFF_PDOUT  = 15269888;  // end 15794176
static constexpr size_t OFF_XW     = 16777216;  // 28928*512*2 -> 46399488 (live 2..6)
static constexpr size_t OFF_QKV    = 46399488;  // 28800*1536*2 -> 134873088 (live 3..4)
static constexpr size_t OFF_ATTNO  = 134873088; // 28800*512*2 -> 164364288 (live 4..5)
static constexpr size_t OFF_PROJS  = OFF_QKV;   // reuse qkvb (dead after attn), live 5..6
static constexpr size_t OFF_INTER  = OFF_XW;    // reuse (all dead), live 8gu..8down
static constexpr size_t OFF_HSB    = 164364288; // 29440*512*2 -> 194510848 (live 6..8gu)
static constexpr size_t OFF_DNOUT  = OFF_ATTNO; // live 8down..9; overruns 512KB into
                                                // dead hsb head (hsb dead after 8gu)

extern "C" void kernel_launch(void* const* d_in, const int* in_sizes, int n_in,
                              void* d_out, int out_size, void* d_ws, size_t ws_size,
                              hipStream_t stream) {
  const float* hs      = (const float*)d_in[0];
  const float* qkv_w   = (const float*)d_in[1];
  const float* qkv_b   = (const float*)d_in[2];
  const float* proj_w  = (const float*)d_in[3];
  const float* proj_b  = (const float*)d_in[4];
  const float* rel_b   = (const float*)d_in[5];
  const float* gu_w    = (const float*)d_in[6];
  const float* down_w  = (const float*)d_in[7];
  const float* pgu_w   = (const float*)d_in[8];
  const float* pdown_w = (const float*)d_in[9];

  char* ws = (char*)d_ws;
  short* Wqkv   = (short*)(ws + OFF_WQKV);
  short* Wproj  = (short*)(ws + OFF_WPROJ);
  short* Wgu    = (short*)(ws + OFF_WGU);
  short* Wdown  = (short*)(ws + OFF_WDOWN);
  short* Wpgu   = (short*)(ws + OFF_WPGU);
  short* Wpdown = (short*)(ws + OFF_WPDOWN);
  float* meanb  = (float*)(ws + OFF_MEAN);
  short* prefb  = (short*)(ws + OFF_PREFB);
  short* pinter = (short*)(ws + OFF_PINTER);
  short* pdout  = (short*)(ws + OFF_PDOUT);
  short* xw     = (short*)(ws + OFF_XW);
  short* qkvb   = (short*)(ws + OFF_QKV);
  short* attno  = (short*)(ws + OFF_ATTNO);
  short* projs  = (short*)(ws + OFF_PROJS);
  short* interb = (short*)(ws + OFF_INTER);
  short* hsb    = (short*)(ws + OFF_HSB);
  short* dnout  = (short*)(ws + OFF_DNOUT);
  float* outf   = (float*)d_out;

  // 1. all weights fp32 -> bf16 (one kernel) + prefix rows
  cvt_all_kernel<<<5632, 256, 0, stream>>>(qkv_w, proj_w, gu_w, down_w,
                                           pgu_w, pdown_w, (short*)ws);
  prefix_cvt_kernel<<<256, 256, 0, stream>>>(hs, prefb);

  // 2. prefix mean -> windowed bf16 input
  mean_kernel<<<32, 512, 0, stream>>>(hs, meanb);
  prep_kernel<<<14400, 256, 0, stream>>>(hs, meanb, xw);

  // 3. QKV projection (M=28800, N=1536, K=512)
  gemm8<EPI_BIAS_BF16><<<dim3(6, 113), 512, 0, stream>>>(
      xw, Wqkv, qkv_b, qkvb, 28800, 1536, 512);
  // 4. windowed attention
  attn_kernel<<<3200, 256, 0, stream>>>(qkvb, rel_b, attno);

  // 5. output projection + scatter (N=512)
  gemm8<EPI_SCATTER><<<dim3(2, 113), 512, 0, stream>>>(
      attno, Wproj, proj_b, projs, 28800, 512, 512);
  // 6. x = rms(xw-residual + proj) -> fp32 d_out + bf16 hsb
  addnorm1_kernel<<<7200, 256, 0, stream>>>(xw, projs, outf, hsb);

  // 7. prefix branch (small): 2-phase gemms + rms
  gemm2<EPI_GU><<<dim3(24, 4), 256, 0, stream>>>(
      prefb, Wpgu, Wpgu + 1536 * 512, nullptr, pinter, 512, 1536, 512);
  gemm2<EPI_BF16><<<dim3(4, 4), 256, 0, stream>>>(
      pinter, Wpdown, nullptr, nullptr, pdout, 512, 512, 1536);
  prefix_addnorm_kernel<<<128, 256, 0, stream>>>(hs, pdout, outf, hsb);

  // 8. full-sequence fused swiglu (M=29312); down writes bf16 dnout
  gemm8gu<<<dim3(12, 115), 512, 0, stream>>>(
      hsb, Wgu, Wgu + 1536 * 512, interb, 29312, 512);
  gemm8<EPI_BF16><<<dim3(2, 115), 512, 0, stream>>>(
      interb, Wdown, nullptr, dnout, 29312, 512, 1536);
  // 9. out = rms(out + dnout) in place
  final_addnorm_kernel<<<7328, 256, 0, stream>>>(dnout, outf);

  (void)in_sizes; (void)n_in; (void)out_size; (void)ws_size;
}